// Round 24
// baseline (224.241 us; speedup 1.0000x reference)
//
#include <hip/hip_runtime.h>
#include <hip/hip_bf16.h>
#include <math.h>

// ---------------------------------------------------------------------------
// FCSwitchedBetaVAE forward. Conv/deconv/FC stack as implicit-GEMM on
// mfma_f32_16x16x32_bf16 (NHWC bf16 activations, f32 accum).
// x is pre-transposed NCHW f32 -> NHWC-pad4 bf16 (one 8B load per conv1 tap).
// Fusions: conv1+conv2 (half-image LDS, 512-thread blocks), conv3+conv4
// (full-image LDS), deconv1+deconv2 (full-image LDS), deconv3+deconv4
// (half-image LDS, kg-XOR bank swizzle, 256-thread blocks).
// B=1024, C=3, L=10, D=192, K=10, S=10.
// ---------------------------------------------------------------------------

#define BATCH 1024

using short8  = __attribute__((ext_vector_type(8))) short;
using f32x4   = __attribute__((ext_vector_type(4))) float;
using ushort4v = __attribute__((ext_vector_type(4))) ushort;

__device__ __forceinline__ ushort f2bf(float f) {
    uint u = __float_as_uint(f);
    uint r = (u + 0x7fffu + ((u >> 16) & 1u)) >> 16;   // RNE
    return (ushort)r;
}
__device__ __forceinline__ float bf2f(ushort u) {
    return __uint_as_float(((uint)u) << 16);
}

// ---------------- merged weight-fragment prep (one dispatch) ---------------
__device__ __forceinline__ void conv_frag_elem(const float* __restrict__ w,
                                               ushort* __restrict__ frag,
                                               int idx, int CIN, int COUT) {
    int NCH = CIN / 32, NT = COUT / 16;
    int j = idx & 7; int lane = (idx >> 3) & 63; int rest = idx >> 9;
    int ntile = rest % NT; rest /= NT;
    int ch = rest % NCH; int tap = rest / NCH;
    int o = ntile * 16 + (lane & 15);
    int i = ch * 32 + (lane >> 4) * 8 + j;
    frag[idx] = f2bf(w[((size_t)(o * CIN + i)) * 16 + tap]);
}
__device__ __forceinline__ void deconv_frag_elem(const float* __restrict__ w,
                                                 ushort* __restrict__ frag,
                                                 int idx, int CIN, int COUT) {
    int NCH = CIN / 32, NT = COUT / 16;
    int j = idx & 7; int lane = (idx >> 3) & 63; int rest = idx >> 9;
    int ntile = rest % NT; rest /= NT;
    int ch = rest % NCH; rest /= NCH;
    int tapidx = rest % 4; int cls = rest / 4;
    int py = cls >> 1, px = cls & 1, a = tapidx >> 1, b = tapidx & 1;
    int tap = (py + 2 * a) * 4 + (px + 2 * b);
    int o = ntile * 16 + (lane & 15);
    int i = ch * 32 + (lane >> 4) * 8 + j;
    frag[idx] = f2bf(w[((size_t)(o * CIN + i)) * 16 + tap]);
}

__global__ __launch_bounds__(256)
void prep_all(const float* __restrict__ cw1, const float* __restrict__ cw2,
              const float* __restrict__ cw3, const float* __restrict__ cw4,
              const float* __restrict__ dw1, const float* __restrict__ dw2,
              const float* __restrict__ dw3, const float* __restrict__ dw4,
              const float* __restrict__ ein_w, const float* __restrict__ fc_w,
              const float* __restrict__ dfc_w,
              ushort* __restrict__ c1g, ushort* __restrict__ c2g,
              ushort* __restrict__ c3g, ushort* __restrict__ c4g,
              ushort* __restrict__ d1g, ushort* __restrict__ d2g,
              ushort* __restrict__ d3g, ushort* __restrict__ d4g,
              ushort* __restrict__ encwTb, ushort* __restrict__ fc1g,
              ushort* __restrict__ dfcg) {
    const int b = blockIdx.x, t = threadIdx.x;
    if (b < 8) {                    // conv1 frag: K = tap*4 + c, c=3 pad
        int idx = b * 256 + t;
        if (idx < 2048) {
            int j = idx & 7; int lane = (idx >> 3) & 63;
            int ntile = (idx >> 9) & 1; int s = idx >> 10;
            int o = ntile * 16 + (lane & 15);
            int kg = lane >> 4;
            int tap = s * 8 + kg * 2 + (j >> 2);
            int c = j & 3;
            c1g[idx] = (c < 3) ? f2bf(cw1[((size_t)(o * 3 + c)) * 16 + tap]) : (ushort)0;
        }
    } else if (b < 72) {
        conv_frag_elem(cw2, c2g, (b - 8) * 256 + t, 32, 32);
    } else if (b < 200) {
        conv_frag_elem(cw3, c3g, (b - 72) * 256 + t, 32, 64);
    } else if (b < 456) {
        conv_frag_elem(cw4, c4g, (b - 200) * 256 + t, 64, 64);
    } else if (b < 712) {
        deconv_frag_elem(dw1, d1g, (b - 456) * 256 + t, 64, 64);
    } else if (b < 840) {
        deconv_frag_elem(dw2, d2g, (b - 712) * 256 + t, 64, 32);
    } else if (b < 904) {
        deconv_frag_elem(dw3, d3g, (b - 840) * 256 + t, 32, 32);
    } else if (b < 936) {           // deconv_last frag, COUT 3 -> padded 16
        int idx = (b - 904) * 256 + t;
        if (idx < 8192) {
            int j = idx & 7; int lane = (idx >> 3) & 63; int rest = idx >> 9;
            int tapidx = rest & 3; int cls = rest >> 2;
            int py = cls >> 1, px = cls & 1, a = tapidx >> 1, bb = tapidx & 1;
            int tap = (py + 2 * a) * 4 + (px + 2 * bb);
            int o = lane & 15;
            int i = (lane >> 4) * 8 + j;
            d4g[idx] = (o < 3) ? f2bf(dw4[((size_t)(o * 32 + i)) * 16 + tap]) : (ushort)0;
        }
    } else if (b < 1686) {          // encoder winT bf16 [L,D,K*S]
        int idx = (b - 936) * 256 + t;
        if (idx < 192000) {
            int ks = idx % 100;
            int d = (idx / 100) % 192;
            int l = idx / 19200;
            int k = ks / 10, s = ks % 10;
            encwTb[idx] = f2bf(ein_w[(size_t)l * 19200 + k * 1920 + d * 10 + s]);
        }
    } else if (b < 2454) {          // fc1 frag
        int idx = (b - 1686) * 256 + t;
        int jj = idx & 7; int lane = (idx >> 3) & 63; int rest = idx >> 9;
        int nt = rest % 12, s = rest / 12;
        int k_nat = s * 32 + (lane >> 4) * 8 + jj;
        int d = (k_nat & 63) * 16 + (k_nat >> 6);
        int j = nt * 16 + (lane & 15);
        fc1g[idx] = f2bf(fc_w[(size_t)d * 192 + j]);
    } else {                        // b < 3222: dfc frag
        int idx = (b - 2454) * 256 + t;
        int jj = idx & 7; int lane = (idx >> 3) & 63; int rest = idx >> 9;
        int nt = rest % 64, s = rest / 64;
        int k = s * 32 + (lane >> 4) * 8 + jj;
        int j_nat = nt * 16 + (lane & 15);
        int d = (j_nat & 63) * 16 + (j_nat >> 6);
        dfcg[idx] = f2bf(dfc_w[(size_t)k * 1024 + d]);
    }
}

// ---- x NCHW f32 [B,3,64,64] -> NHWC-pad4 bf16 [B,64,64,4] -----------------
// Fully coalesced: 3 float4 reads + 2 short8 writes per 4 pixels.
__global__ __launch_bounds__(256)
void nchw2nhwc(const float* __restrict__ x, ushort* __restrict__ xh) {
    const int n = blockIdx.x;
    const float* xb = x + (size_t)n * 12288;
    ushort* ob = xh + ((size_t)n << 14);
    #pragma unroll
    for (int i = 0; i < 4; ++i) {
        const int p0 = (i * 256 + threadIdx.x) << 2;   // 4 pixels
        const float4 v0 = *(const float4*)(xb + p0);
        const float4 v1 = *(const float4*)(xb + 4096 + p0);
        const float4 v2 = *(const float4*)(xb + 8192 + p0);
        short8 o0, o1;
        o0[0] = (short)f2bf(v0.x); o0[1] = (short)f2bf(v1.x); o0[2] = (short)f2bf(v2.x); o0[3] = 0;
        o0[4] = (short)f2bf(v0.y); o0[5] = (short)f2bf(v1.y); o0[6] = (short)f2bf(v2.y); o0[7] = 0;
        o1[0] = (short)f2bf(v0.z); o1[1] = (short)f2bf(v1.z); o1[2] = (short)f2bf(v2.z); o1[3] = 0;
        o1[4] = (short)f2bf(v0.w); o1[5] = (short)f2bf(v1.w); o1[6] = (short)f2bf(v2.w); o1[7] = 0;
        *(short8*)(ob + (size_t)(p0 << 2)) = o0;
        *(short8*)(ob + (size_t)(p0 << 2) + 8) = o1;
    }
}

// ---- FUSED conv1+conv2: xh NHWC bf16 [B,64,64,4] -> bufB [B,16,16,32] -----
// B*2 blocks x 512 threads (8 waves). Phase A: conv1 rows my = 16h-1..16h+16
// into LDS mid[576][40] bf16; one 8B load per tap (4 loads/gather, 0 cvt).
// Phase B: conv2 output rows [8h, 8h+8).
__global__ __launch_bounds__(512)
void conv12_fused(const ushort* __restrict__ xh, const ushort* __restrict__ w1frag,
                  const float* __restrict__ b1, const ushort* __restrict__ w2frag,
                  const float* __restrict__ b2, ushort* __restrict__ out) {
    __shared__ ushort mid[576 * 40];   // 46080 B
    const int t = threadIdx.x;
    const int lane = t & 63, w = t >> 6;   // w in [0,8)
    const int m = lane & 15, kg = lane >> 4;
    const int h = blockIdx.x & 1, n = blockIdx.x >> 1;
    const int base = 16 * h - 1;
    const ushort* xb = xh + ((size_t)n << 14);

    short8 bf1[4];
    #pragma unroll
    for (int f = 0; f < 4; ++f)
        bf1[f] = *(const short8*)(w1frag + (f << 9) + lane * 8);

    auto gatherA = [&](int mt, short8* av) {
        const int lp = mt * 16 + m;
        const int lx = lp & 31, lyy = lp >> 5;
        const int my = base + lyy;
        const int iy0 = 2 * my - 1, ix0 = 2 * lx - 1;
        #pragma unroll
        for (int s = 0; s < 2; ++s) {
            union { ushort4v h4[2]; short8 s8; } a;
            #pragma unroll
            for (int tt = 0; tt < 2; ++tt) {
                const int tap = s * 8 + kg * 2 + tt;
                const int ky = tap >> 2, kx = tap & 3;
                const int iy = iy0 + ky, ix = ix0 + kx;
                ushort4v v = {0, 0, 0, 0};
                if ((unsigned)iy < 64u && (unsigned)ix < 64u)
                    v = *(const ushort4v*)(xb + (size_t)(((iy << 6) + ix) << 2));
                a.h4[tt] = v;
            }
            av[s] = a.s8;
        }
    };
    auto commitA = [&](int mt, short8* av) {
        f32x4 acc[2] = {{0,0,0,0},{0,0,0,0}};
        #pragma unroll
        for (int s = 0; s < 2; ++s)
            #pragma unroll
            for (int nt = 0; nt < 2; ++nt)
                acc[nt] = __builtin_amdgcn_mfma_f32_16x16x32_bf16(av[s], bf1[s * 2 + nt], acc[nt], 0, 0, 0);
        #pragma unroll
        for (int nt = 0; nt < 2; ++nt) {
            const int och = (nt << 4) + m;
            const float bv = b1[och];
            #pragma unroll
            for (int r = 0; r < 4; ++r) {
                const int lpr = (mt << 4) + (kg << 2) + r;
                mid[(size_t)lpr * 40 + och] = f2bf(fmaxf(acc[nt][r] + bv, 0.f));
            }
        }
    };

    // -------- phase A: 36 mtiles / 8 waves, 2-way unrolled -----
    {
        short8 avA[2], avB[2];
        gatherA(w, avA);
        gatherA(w + 8, avB);
        commitA(w, avA);
        commitA(w + 8, avB);
        gatherA(w + 16, avA);
        gatherA(w + 24, avB);
        commitA(w + 16, avA);
        commitA(w + 24, avB);
        if (w < 4) {
            gatherA(w + 32, avA);
            commitA(w + 32, avA);
        }
    }
    __syncthreads();
    // -------- phase B: conv2, 16 combos / 8 waves --------
    for (int it = 0; it < 2; ++it) {
        const int u = it * 8 + w;            // 0..15
        const int nt = u & 1, mt2 = u >> 1;  // mt2 0..7
        const int p2 = (mt2 << 4) + m;
        const int ox2 = p2 & 15, ly2 = p2 >> 4;
        const int oy2 = 8 * h + ly2;
        const int iy0 = 2 * oy2 - 1, ix0 = 2 * ox2 - 1;
        f32x4 acc = {0, 0, 0, 0};
        const ushort* wl = w2frag + ((size_t)nt << 9) + lane * 8;
        #pragma unroll
        for (int ky = 0; ky < 4; ++ky) {
            const int iy = iy0 + ky;
            const bool vy = (unsigned)iy < 32u;
            const int liy = iy - base;
            #pragma unroll
            for (int kx = 0; kx < 4; ++kx) {
                const int ix = ix0 + kx;
                const bool v = vy && ((unsigned)ix < 32u);
                short8 a = {0, 0, 0, 0, 0, 0, 0, 0};
                if (v) a = *(const short8*)(mid + (size_t)((liy << 5) + ix) * 40 + kg * 8);
                const short8 b = *(const short8*)(wl + ((size_t)((ky * 4 + kx) * 2) << 9));
                acc = __builtin_amdgcn_mfma_f32_16x16x32_bf16(a, b, acc, 0, 0, 0);
            }
        }
        const int och = (nt << 4) + m;
        const float bv = b2[och];
        ushort* ob = out + ((size_t)n * 256 + 128 * h + (mt2 << 4) + (kg << 2)) * 32;
        #pragma unroll
        for (int r = 0; r < 4; ++r)
            ob[r * 32 + och] = f2bf(fmaxf(acc[r] + bv, 0.f));
    }
}

// ---- FUSED conv3+conv4: bufB [B,16,16,32] -> bufD [B*16][64] --------------
__global__ __launch_bounds__(256)
void conv34_fused(const ushort* __restrict__ in, const ushort* __restrict__ w3frag,
                  const float* __restrict__ b3, const ushort* __restrict__ w4frag,
                  const float* __restrict__ b4, ushort* __restrict__ out) {
    __shared__ ushort mid[64 * 64];   // 8192 B
    const int t = threadIdx.x;
    const int lane = t & 63, w = t >> 6;
    const int m = lane & 15, kg = lane >> 4;
    const int n = blockIdx.x;
    const ushort* ibase = in + ((size_t)n << 13);   // 16*16*32

    // -------- phase A: conv3 (CIN=32,COUT=64,HIN=16) --------
    {
        const int p = (w << 4) + m;          // pixel 0..63
        const int ox = p & 7, oy = p >> 3;
        const int iy0 = 2 * oy - 1, ix0 = 2 * ox - 1;
        f32x4 acc[4] = {{0,0,0,0},{0,0,0,0},{0,0,0,0},{0,0,0,0}};
        #pragma unroll
        for (int ky = 0; ky < 4; ++ky) {
            const int iy = iy0 + ky;
            const bool vy = (unsigned)iy < 16u;
            #pragma unroll
            for (int kx = 0; kx < 4; ++kx) {
                const int ix = ix0 + kx;
                const bool v = vy && ((unsigned)ix < 16u);
                short8 a = {0, 0, 0, 0, 0, 0, 0, 0};
                if (v) a = *(const short8*)(ibase + (size_t)((iy << 4) + ix) * 32 + kg * 8);
                const int tap = ky * 4 + kx;
                #pragma unroll
                for (int nt = 0; nt < 4; ++nt) {
                    const short8 b = *(const short8*)(w3frag + ((size_t)(tap * 4 + nt) << 9) + lane * 8);
                    acc[nt] = __builtin_amdgcn_mfma_f32_16x16x32_bf16(a, b, acc[nt], 0, 0, 0);
                }
            }
        }
        #pragma unroll
        for (int nt = 0; nt < 4; ++nt) {
            const int och = (nt << 4) + m;
            const float bv = b3[och];
            #pragma unroll
            for (int r = 0; r < 4; ++r) {
                const int pr = (w << 4) + (kg << 2) + r;
                mid[(size_t)pr * 64 + och] = f2bf(fmaxf(acc[nt][r] + bv, 0.f));
            }
        }
    }
    __syncthreads();
    // -------- phase B: conv4 (CIN=64,COUT=64,HIN=8), wave = ntile --------
    {
        const int ox = m & 3, oy = m >> 2;
        const int iy0 = 2 * oy - 1, ix0 = 2 * ox - 1;
        f32x4 acc = {0, 0, 0, 0};
        const ushort* wl = w4frag + ((size_t)w << 9) + lane * 8;
        #pragma unroll
        for (int ky = 0; ky < 4; ++ky) {
            const int iy = iy0 + ky;
            const bool vy = (unsigned)iy < 8u;
            #pragma unroll
            for (int kx = 0; kx < 4; ++kx) {
                const int ix = ix0 + kx;
                const bool v = vy && ((unsigned)ix < 8u);
                const int tap = ky * 4 + kx;
                #pragma unroll
                for (int ch = 0; ch < 2; ++ch) {
                    short8 a = {0, 0, 0, 0, 0, 0, 0, 0};
                    if (v) a = *(const short8*)(mid + (size_t)((iy << 3) + ix) * 64 + ch * 32 + kg * 8);
                    const short8 b = *(const short8*)(wl + ((size_t)((tap * 2 + ch) * 4) << 9));
                    acc = __builtin_amdgcn_mfma_f32_16x16x32_bf16(a, b, acc, 0, 0, 0);
                }
            }
        }
        const int och = (w << 4) + m;
        const float bv = b4[och];
        #pragma unroll
        for (int r = 0; r < 4; ++r)
            out[((size_t)n * 16 + (kg << 2) + r) * 64 + och] = f2bf(fmaxf(acc[r] + bv, 0.f));
    }
}

// ---- FUSED deconv1+deconv2: bufD [B][4,4,64] -> bufB [B,16,16,32] ---------
__global__ __launch_bounds__(256)
void deconv12_fused(const ushort* __restrict__ in, const ushort* __restrict__ w1frag,
                    const float* __restrict__ b1, const ushort* __restrict__ w2frag,
                    const float* __restrict__ b2, ushort* __restrict__ out) {
    __shared__ ushort mid[64 * 64];   // 8192 B
    const int t = threadIdx.x;
    const int lane = t & 63, w = t >> 6;
    const int m = lane & 15, kg = lane >> 4;
    const int n = blockIdx.x;
    const ushort* ibase = in + ((size_t)n << 10);   // 4*4*64

    // -------- phase A: deconv1 (CIN=64,COUT=64,HIN=4), wave = ntile --------
    {
        const int oxh = m & 3, oyh = m >> 2;
        f32x4 acc[4] = {{0,0,0,0},{0,0,0,0},{0,0,0,0},{0,0,0,0}};
        const ushort* wl = w1frag + ((size_t)w << 9) + lane * 8;
        #pragma unroll
        for (int ch = 0; ch < 2; ++ch) {
            short8 nb[3][3];
            #pragma unroll
            for (int dy = 0; dy < 3; ++dy) {
                const int iy = oyh + dy - 1;
                const bool vy = (unsigned)iy < 4u;
                #pragma unroll
                for (int dx = 0; dx < 3; ++dx) {
                    const int ix = oxh + dx - 1;
                    short8 a = {0, 0, 0, 0, 0, 0, 0, 0};
                    if (vy && (unsigned)ix < 4u)
                        a = *(const short8*)(ibase + (size_t)((iy << 2) + ix) * 64 + ch * 32 + kg * 8);
                    nb[dy][dx] = a;
                }
            }
            #pragma unroll
            for (int cls = 0; cls < 4; ++cls) {
                const int py = cls >> 1, px = cls & 1;
                #pragma unroll
                for (int ti = 0; ti < 4; ++ti) {
                    const int a2 = ti >> 1, b2i = ti & 1;
                    const short8 b = *(const short8*)(wl + ((size_t)(((cls * 4 + ti) * 2 + ch) * 4) << 9));
                    acc[cls] = __builtin_amdgcn_mfma_f32_16x16x32_bf16(nb[py + a2][px + b2i], b, acc[cls], 0, 0, 0);
                }
            }
        }
        const int och = (w << 4) + m;
        const float bv = b1[och];
        #pragma unroll
        for (int cls = 0; cls < 4; ++cls) {
            const int py = cls >> 1, px = cls & 1;
            #pragma unroll
            for (int r = 0; r < 4; ++r) {
                const int qq = (kg << 2) + r;
                const int oxh2 = qq & 3, oyh2 = qq >> 2;
                const int oy = 2 * oyh2 + py, ox = 2 * oxh2 + px;
                mid[(size_t)((oy << 3) + ox) * 64 + och] = f2bf(fmaxf(acc[cls][r] + bv, 0.f));
            }
        }
    }
    __syncthreads();
    // -------- phase B: deconv2 (CIN=64,COUT=32,HIN=8), 8 combos / 4 waves --
    for (int u = w; u < 8; u += 4) {
        const int nt = u & 1, mt = u >> 1;
        const int q = (mt << 4) + m;
        const int oxh = q & 7, oyh = q >> 3;
        f32x4 acc[4] = {{0,0,0,0},{0,0,0,0},{0,0,0,0},{0,0,0,0}};
        const ushort* wl = w2frag + ((size_t)nt << 9) + lane * 8;
        #pragma unroll
        for (int ch = 0; ch < 2; ++ch) {
            short8 nb[3][3];
            #pragma unroll
            for (int dy = 0; dy < 3; ++dy) {
                const int iy = oyh + dy - 1;
                const bool vy = (unsigned)iy < 8u;
                #pragma unroll
                for (int dx = 0; dx < 3; ++dx) {
                    const int ix = oxh + dx - 1;
                    short8 a = {0, 0, 0, 0, 0, 0, 0, 0};
                    if (vy && (unsigned)ix < 8u)
                        a = *(const short8*)(mid + (size_t)((iy << 3) + ix) * 64 + ch * 32 + kg * 8);
                    nb[dy][dx] = a;
                }
            }
            #pragma unroll
            for (int cls = 0; cls < 4; ++cls) {
                const int py = cls >> 1, px = cls & 1;
                #pragma unroll
                for (int ti = 0; ti < 4; ++ti) {
                    const int a2 = ti >> 1, b2i = ti & 1;
                    const short8 b = *(const short8*)(wl + ((size_t)(((cls * 4 + ti) * 2 + ch) * 2) << 9));
                    acc[cls] = __builtin_amdgcn_mfma_f32_16x16x32_bf16(nb[py + a2][px + b2i], b, acc[cls], 0, 0, 0);
                }
            }
        }
        const int och = (nt << 4) + m;
        const float bv = b2[och];
        #pragma unroll
        for (int cls = 0; cls < 4; ++cls) {
            const int py = cls >> 1, px = cls & 1;
            #pragma unroll
            for (int r = 0; r < 4; ++r) {
                const int qq = (mt << 4) + (kg << 2) + r;
                const int oxh2 = qq & 7, oyh2 = qq >> 3;
                const int oy = 2 * oyh2 + py, ox = 2 * oxh2 + px;
                out[((size_t)(n * 16 + oy) * 16 + ox) * 32 + och] = f2bf(fmaxf(acc[cls][r] + bv, 0.f));
            }
        }
    }
}

// ---- FUSED deconv3+deconv4: bufB [B,16,16,32] -> recon NCHW f32 [B,3,64,64]
// B*2 blocks x 256 threads. mid uses kg-XOR channel swizzle: writer kg ==
// (pix>>3)&3, stored at och ^ (kg<<3); reader recovers (kg ^ ((ix>>3)&3))*8.
__global__ __launch_bounds__(256)
void deconv34_fused(const ushort* __restrict__ in, const ushort* __restrict__ w3frag,
                    const float* __restrict__ b3, const ushort* __restrict__ w4frag,
                    const float* __restrict__ b4, float* __restrict__ out) {
    __shared__ ushort mid[20 * 32 * 32];   // 40960 B
    const int t = threadIdx.x;
    const int lane = t & 63, w = t >> 6;
    const int m = lane & 15, kg = lane >> 4;
    const int h = blockIdx.x & 1, n = blockIdx.x >> 1;
    const int base = 16 * h - 2;
    const ushort* ibase = in + ((size_t)n << 13);   // 16*16*32

    // -------- phase A: deconv3 rows ir = 8h-1 .. 8h+8 --> mid --------
    for (int u = w; u < 20; u += 4) {
        const int nt = u & 1, mt = u >> 1;
        const int ir = 8 * h - 1 + mt;
        short8 nb[3][3];
        #pragma unroll
        for (int dy = 0; dy < 3; ++dy) {
            const int iy = ir + dy - 1;
            const bool vy = (unsigned)iy < 16u;
            #pragma unroll
            for (int dx = 0; dx < 3; ++dx) {
                const int ix = m + dx - 1;
                short8 a = {0, 0, 0, 0, 0, 0, 0, 0};
                if (vy && (unsigned)ix < 16u)
                    a = *(const short8*)(ibase + (size_t)((iy << 4) + ix) * 32 + kg * 8);
                nb[dy][dx] = a;
            }
        }
        const ushort* wl = w3frag + ((size_t)nt << 9) + lane * 8;
        f32x4 acc[4] = {{0,0,0,0},{0,0,0,0},{0,0,0,0},{0,0,0,0}};
        #pragma unroll
        for (int cls = 0; cls < 4; ++cls) {
            const int py = cls >> 1, px = cls & 1;
            #pragma unroll
            for (int ti = 0; ti < 4; ++ti) {
                const int a2 = ti >> 1, b2 = ti & 1;
                const short8 b = *(const short8*)(wl + ((size_t)((cls * 4 + ti) * 2) << 9));
                acc[cls] = __builtin_amdgcn_mfma_f32_16x16x32_bf16(nb[py + a2][px + b2], b, acc[cls], 0, 0, 0);
            }
        }
        const int och = (nt << 4) + m;
        const int ochSw = och ^ (kg << 3);   // bank swizzle (writer kg)
        const float bv = b3[och];
        #pragma unroll
        for (int cls = 0; cls < 4; ++cls) {
            const int py = cls >> 1, px = cls & 1;
            const int ly = 2 * mt + py;
            #pragma unroll
            for (int r = 0; r < 4; ++r) {
                const int ox = ((kg << 3) + 2 * r) + px;
                mid[(size_t)((ly << 5) + ox) * 32 + ochSw] = f2bf(fmaxf(acc[cls][r] + bv, 0.f));
            }
        }
    }
    __syncthreads();
    // -------- phase B: deconv_last, output rows [32h, 32h+32) --------
    for (int it = 0; it < 8; ++it) {
        const int mt2 = it * 4 + w;
        const int oyh = 16 * h + (mt2 >> 1);
        const int oxh = ((mt2 & 1) << 4) + m;
        short8 nb[3][3];
        #pragma unroll
        for (int dy = 0; dy < 3; ++dy) {
            const int iy = oyh + dy - 1;
            const bool vy = (unsigned)iy < 32u;
            const int ly = iy - base;
            #pragma unroll
            for (int dx = 0; dx < 3; ++dx) {
                const int ix = oxh + dx - 1;
                short8 a = {0, 0, 0, 0, 0, 0, 0, 0};
                if (vy && (unsigned)ix < 32u) {
                    const int rb = (kg ^ ((ix >> 3) & 3)) << 3;   // un-swizzle
                    a = *(const short8*)(mid + (size_t)((ly << 5) + ix) * 32 + rb);
                }
                nb[dy][dx] = a;
            }
        }
        f32x4 acc[4] = {{0,0,0,0},{0,0,0,0},{0,0,0,0},{0,0,0,0}};
        const ushort* wl = w4frag + lane * 8;
        #pragma unroll
        for (int cls = 0; cls < 4; ++cls) {
            const int py = cls >> 1, px = cls & 1;
            #pragma unroll
            for (int ti = 0; ti < 4; ++ti) {
                const int a2 = ti >> 1, b2 = ti & 1;
                const short8 b = *(const short8*)(wl + ((cls * 4 + ti) << 9));
                acc[cls] = __builtin_amdgcn_mfma_f32_16x16x32_bf16(nb[py + a2][px + b2], b, acc[cls], 0, 0, 0);
            }
        }
        if (m < 3) {
            const float bv = b4[m];
            float* ob = out + (size_t)n * 12288 + m * 4096;
            #pragma unroll
            for (int r = 0; r < 4; ++r) {
                const int x = ((mt2 & 1) << 4) + (kg << 2) + r;
                #pragma unroll
                for (int py = 0; py < 2; ++py) {
                    float2 v = {acc[py * 2 + 0][r] + bv, acc[py * 2 + 1][r] + bv};
                    *(float2*)(ob + (2 * oyh + py) * 64 + 2 * x) = v;
                }
            }
        }
    }
}

// ---------------- fc1 MFMA: bufD [B,1024] bf16 -> bufH [B,192] f32 ---------
__global__ __launch_bounds__(256)
void fc1_mfma(const ushort* __restrict__ in, const ushort* __restrict__ frag,
              const float* __restrict__ bias, float* __restrict__ out) {
    const int lane = threadIdx.x & 63;
    const int gw = (blockIdx.x << 2) + (threadIdx.x >> 6);   // [0,768)
    const int nt = gw % 12, mt = gw / 12;
    const int m = lane & 15, kg = lane >> 4;
    const ushort* arow = in + ((size_t)(mt * 16 + m) << 10) + kg * 8;
    const ushort* wl = frag + nt * 512 + lane * 8;
    f32x4 acc0 = {0, 0, 0, 0}, acc1 = {0, 0, 0, 0};
    #pragma unroll
    for (int s = 0; s < 32; s += 2) {
        const short8 a0 = *(const short8*)(arow + s * 32);
        const short8 a1 = *(const short8*)(arow + s * 32 + 32);
        const short8 b0 = *(const short8*)(wl + ((size_t)(s * 12) << 9));
        const short8 b1 = *(const short8*)(wl + ((size_t)((s + 1) * 12) << 9));
        acc0 = __builtin_amdgcn_mfma_f32_16x16x32_bf16(a0, b0, acc0, 0, 0, 0);
        acc1 = __builtin_amdgcn_mfma_f32_16x16x32_bf16(a1, b1, acc1, 0, 0, 0);
    }
    const int j = nt * 16 + m;
    const float bv = bias[j];
    #pragma unroll
    for (int r = 0; r < 4; ++r)
        out[(size_t)(mt * 16 + kg * 4 + r) * 192 + j] = (acc0[r] + acc1[r]) + bv;
}

// --------- dfc MFMA: dbf [B,192] bf16 -> bufD [B,1024] bf16 (NHWC), relu ---
__global__ __launch_bounds__(256)
void dfc_mfma(const ushort* __restrict__ in, const ushort* __restrict__ frag,
              const float* __restrict__ bias, ushort* __restrict__ out) {
    const int lane = threadIdx.x & 63;
    const int gw = (blockIdx.x << 2) + (threadIdx.x >> 6);   // [0,1024)
    const int ntg = gw & 15, mt = gw >> 4;
    const int m = lane & 15, kg = lane >> 4;
    const ushort* arow = in + (size_t)(mt * 16 + m) * 192 + kg * 8;
    const ushort* wl = frag + ((size_t)(ntg * 4) << 9) + lane * 8;
    f32x4 acc[4] = {{0,0,0,0},{0,0,0,0},{0,0,0,0},{0,0,0,0}};
    #pragma unroll
    for (int s = 0; s < 6; ++s) {
        const short8 a = *(const short8*)(arow + s * 32);
        #pragma unroll
        for (int q = 0; q < 4; ++q) {
            const short8 b = *(const short8*)(wl + ((size_t)(s * 64 + q) << 9));
            acc[q] = __builtin_amdgcn_mfma_f32_16x16x32_bf16(a, b, acc[q], 0, 0, 0);
        }
    }
    #pragma unroll
    for (int q = 0; q < 4; ++q) {
        const int j_nat = (ntg * 4 + q) * 16 + m;
        const int d = (j_nat & 63) * 16 + (j_nat >> 6);
        const float bv = bias[d];
        #pragma unroll
        for (int r = 0; r < 4; ++r) {
            const float vv = fmaxf(acc[q][r] + bv, 0.f);
            out[((size_t)(mt * 16 + kg * 4 + r) << 10) + j_nat] = f2bf(vv);
        }
    }
}

// ---- encoder switch chain: 4 rows/block, bf16 winT, ILP-4 VALU hid --------
__global__ __launch_bounds__(256)
void enc_switch4(float* __restrict__ h,
                 const ushort* __restrict__ winTb,   // [L,192,100] bf16
                 const float* __restrict__ bin_all,  // [L,100]
                 const float* __restrict__ wout_all, // [L,K,10,192]
                 const float* __restrict__ bout_all, // [L,K,192]
                 const float* __restrict__ wsw_all,  // [L,K,10]
                 const float* __restrict__ bsw_all,  // [L,K]
                 const float* __restrict__ gn_all,   // [L,B,10]
                 int* __restrict__ yidx, float* __restrict__ gateArr) {
    const int t = threadIdx.x;
    const int b0 = blockIdx.x << 2;
    __shared__ float hold[4][192], r[4][192], part[4][200], hid[4][100], lg[4][10];
    __shared__ int yi_s[4]; __shared__ float gate_s[4];
    if (t < 192) {
        #pragma unroll
        for (int row = 0; row < 4; ++row) {
            const float v = h[(size_t)(b0 + row) * 192 + t];
            hold[row][t] = v; r[row][t] = fmaxf(v, 0.f);
        }
    }
    for (int i = 0; i < 10; ++i) {
        __syncthreads();   // r ready
        if (t < 200) {
            const int ks = (t < 100) ? t : t - 100;
            const int half = (t < 100) ? 0 : 1;
            const ushort* wp = winTb + (size_t)i * 19200 + (half * 96) * 100 + ks;
            const float* r0 = &r[0][half * 96];
            const float* r1 = &r[1][half * 96];
            const float* r2 = &r[2][half * 96];
            const float* r3 = &r[3][half * 96];
            float a0 = 0.f, a1 = 0.f, a2 = 0.f, a3 = 0.f;
            #pragma unroll
            for (int dd = 0; dd < 96; ++dd) {
                const float wv = bf2f(wp[dd * 100]);
                a0 = fmaf(r0[dd], wv, a0);
                a1 = fmaf(r1[dd], wv, a1);
                a2 = fmaf(r2[dd], wv, a2);
                a3 = fmaf(r3[dd], wv, a3);
            }
            part[0][t] = a0; part[1][t] = a1; part[2][t] = a2; part[3][t] = a3;
        }
        __syncthreads();
        if (t < 100) {
            const float bv = bin_all[i * 100 + t];
            #pragma unroll
            for (int row = 0; row < 4; ++row)
                hid[row][t] = part[row][t] + part[row][t + 100] + bv;
        }
        __syncthreads();
        if (t < 40) {
            const int row = t / 10, k = t % 10;
            const float* wsw = wsw_all + i * 100 + k * 10;
            float acc = bsw_all[i * 10 + k];
            #pragma unroll
            for (int s = 0; s < 10; ++s) acc = fmaf(hid[row][k * 10 + s], wsw[s], acc);
            lg[row][k] = acc - logf(gn_all[(size_t)i * 10240 + (b0 + row) * 10 + k] + 1e-20f);
        }
        __syncthreads();
        if (t < 4) {
            int bi = 0; float best = lg[t][0];
            #pragma unroll
            for (int k = 1; k < 10; ++k) if (lg[t][k] > best) { best = lg[t][k]; bi = k; }
            float sum = 0.f;
            #pragma unroll
            for (int k = 0; k < 10; ++k) sum += expf(lg[t][k] - best);
            const float ysoft = 1.0f / sum;
            yi_s[t] = bi;
            const float g = (1.0f - ysoft) + ysoft;
            gate_s[t] = g;
            yidx[i * 1024 + b0 + t] = bi;
            gateArr[i * 1024 + b0 + t] = g;
        }
        __syncthreads();
        if (t < 192) {
            #pragma unroll
            for (int row = 0; row < 4; ++row) {
                const int yi = yi_s[row];
                const float gate = gate_s[row];
                const float* wb = wout_all + (size_t)i * 19200 + yi * 1920 + t;
                float acc = bout_all[i * 1920 + yi * 192 + t];
                #pragma unroll
                for (int s = 0; s < 10; ++s) acc = fmaf(hid[row][yi * 10 + s], wb[s * 192], acc);
                const float nv = hold[row][t] + acc * gate;
                hold[row][t] = nv; r[row][t] = fmaxf(nv, 0.f);
            }
        }
    }
    __syncthreads();
    if (t < 192) {
        #pragma unroll
        for (int row = 0; row < 4; ++row)
            h[(size_t)(b0 + row) * 192 + t] = hold[row][t];
    }
}

// ------- fused decoder switch chain; emits bf16 relu'd state for dfc -------
__global__ __launch_bounds__(256)
void dec_switch_all(const float* __restrict__ h,
                    const float* __restrict__ win_all,   // [L,K,192,10]
                    const float* __restrict__ bin_all,   // [L,K,10]
                    const float* __restrict__ wout_all,  // [L,K,10,192]
                    const float* __restrict__ bout_all,  // [L,K,192]
                    const int* __restrict__ yidx, const float* __restrict__ gateArr,
                    ushort* __restrict__ dbf) {
    const int b = blockIdx.x, t = threadIdx.x;
    __shared__ float hold[192], r[192], part[240], hid[10];
    if (t < 192) { float v = h[(size_t)b * 192 + t]; hold[t] = v; r[t] = fmaxf(v, 0.f); }
    for (int i = 0; i < 10; ++i) {
        const int yi = yidx[i * 1024 + b];
        const float gate = gateArr[i * 1024 + b];
        __syncthreads();   // r ready
        if (t < 240) {
            const int s = t % 10, g = t / 10;     // 24 groups x 8 d's
            const float* wp = win_all + (size_t)i * 19200 + yi * 1920 + s;
            const int d0 = g * 8;
            float a0 = 0.f, a1 = 0.f;
            #pragma unroll
            for (int dd = 0; dd < 8; dd += 2) {
                a0 = fmaf(r[d0 + dd + 0], wp[(d0 + dd + 0) * 10], a0);
                a1 = fmaf(r[d0 + dd + 1], wp[(d0 + dd + 1) * 10], a1);
            }
            part[t] = a0 + a1;
        }
        __syncthreads();
        if (t < 10) {
            float acc = bin_all[i * 100 + yi * 10 + t];
            #pragma unroll
            for (int g = 0; g < 24; ++g) acc += part[g * 10 + t];
            hid[t] = acc;
        }
        __syncthreads();
        if (t < 192) {
            const float* wp = wout_all + (size_t)i * 19200 + yi * 1920 + t;
            float acc = bout_all[i * 1920 + yi * 192 + t];
            #pragma unroll
            for (int s = 0; s < 10; ++s) acc = fmaf(hid[s], wp[s * 192], acc);
            float nv = hold[t] + acc * gate;
            hold[t] = nv; r[t] = fmaxf(nv, 0.f);
        }
    }
    if (t < 192) dbf[(size_t)b * 192 + t] = f2bf(r[t]);
}

// ------- z stats + reparameterize + decoder input FC -----------------------
__global__ __launch_bounds__(192)
void zfcl_kernel(const float* __restrict__ h,
                 const float* __restrict__ mw, const float* __restrict__ mb,
                 const float* __restrict__ lw, const float* __restrict__ lb,
                 const float* __restrict__ zn,
                 const float* __restrict__ fw, const float* __restrict__ fb,
                 float* __restrict__ out_z, float* __restrict__ out_mean,
                 float* __restrict__ out_lv, float* __restrict__ dbuf) {
    const int b = blockIdx.x, t = threadIdx.x;
    __shared__ float r[192], pm[160], pl[160], zsh[10];
    for (int d = t; d < 192; d += 192) r[d] = fmaxf(h[(size_t)b * 192 + d], 0.f);
    __syncthreads();
    if (t < 160) {
        const int l = t % 10, g = t / 10;
        float am = 0.f, al = 0.f;
        #pragma unroll
        for (int d = g * 12; d < g * 12 + 12; ++d) {
            am = fmaf(r[d], mw[d * 10 + l], am);
            al = fmaf(r[d], lw[d * 10 + l], al);
        }
        pm[t] = am; pl[t] = al;
    }
    __syncthreads();
    if (t < 10) {
        float zm = mb[t], zl = lb[t];
        #pragma unroll
        for (int g = 0; g < 16; ++g) { zm += pm[g * 10 + t]; zl += pl[g * 10 + t]; }
        const float z = zn[(size_t)b * 10 + t] * expf(zl * 0.5f) + zm;
        out_mean[(size_t)b * 10 + t] = zm;
        out_lv[(size_t)b * 10 + t] = zl;
        out_z[(size_t)b * 10 + t] = z;
        zsh[t] = z;
    }
    __syncthreads();
    for (int d = t; d < 192; d += 192) {
        float acc = fb[d];
        #pragma unroll
        for (int l = 0; l < 10; ++l) acc = fmaf(zsh[l], fw[l * 192 + d], acc);
        dbuf[(size_t)b * 192 + d] = acc;
    }
}

// ---------------------------------------------------------------------------
extern "C" void kernel_launch(void* const* d_in, const int* in_sizes, int n_in,
                              void* d_out, int out_size, void* d_ws, size_t ws_size,
                              hipStream_t stream) {
    const float* x      = (const float*)d_in[0];
    const float* gnoise = (const float*)d_in[1];
    const float* znoise = (const float*)d_in[2];
    const float* cw1 = (const float*)d_in[3];  const float* cb1 = (const float*)d_in[4];
    const float* cw2 = (const float*)d_in[5];  const float* cb2 = (const float*)d_in[6];
    const float* cw3 = (const float*)d_in[7];  const float* cb3 = (const float*)d_in[8];
    const float* cw4 = (const float*)d_in[9];  const float* cb4 = (const float*)d_in[10];
    const float* fc_w = (const float*)d_in[11]; const float* fc_b = (const float*)d_in[12];
    const float* ein_w = (const float*)d_in[13]; const float* ein_b = (const float*)d_in[14];
    const float* eout_w = (const float*)d_in[15]; const float* eout_b = (const float*)d_in[16];
    const float* esw_w = (const float*)d_in[17]; const float* esw_b = (const float*)d_in[18];
    const float* mean_w = (const float*)d_in[19]; const float* mean_b = (const float*)d_in[20];
    const float* lv_w = (const float*)d_in[21]; const float* lv_b = (const float*)d_in[22];
    const float* fcl_w = (const float*)d_in[23]; const float* fcl_b = (const float*)d_in[24];
    const float* din_w = (const float*)d_in[25]; const float* din_b = (const float*)d_in[26];
    const float* dout_w = (const float*)d_in[27]; const float* dout_b = (const float*)d_in[28];
    const float* dfc_w = (const float*)d_in[29]; const float* dfc_b = (const float*)d_in[30];
    const float* dw1 = (const float*)d_in[31]; const float* db1 = (const float*)d_in[32];
    const float* dw2 = (const float*)d_in[33]; const float* db2 = (const float*)d_in[34];
    const float* dw3 = (const float*)d_in[35]; const float* db3 = (const float*)d_in[36];
    const float* dw4 = (const float*)d_in[37]; const float* db4 = (const float*)d_in[38];

    float* out = (float*)d_out;
    float* recon  = out;
    float* z_out  = out + 12582912;
    float* zm_out = z_out + 10240;
    float* zl_out = zm_out + 10240;

    char* ws = (char*)d_ws;
    ushort* xh    = (ushort*)(ws);                  // [B,64,64,4] bf16 33.6 MB
    ushort* bufB  = (ushort*)(ws + 100663296);      // [B,16,16,32] 16.8 MB
    ushort* bufD  = (ushort*)(ws + 125829120);      // [B*16][64]   2.1 MB
    float*  bufH  = (float*) (ws + 127926272);      // [B,192]
    float*  bufD2 = (float*) (ws + 128712704);      // [B,192]
    int*    yidx  = (int*)   (ws + 129499136);
    float*  gate  = (float*) (ws + 129540096);
    char*   fb    = ws + 129581056;
    ushort* c1g = (ushort*)(fb);                    //   4096 B
    ushort* c2g = (ushort*)(fb + 4096);             //  32768 B
    ushort* c3g = (ushort*)(fb + 36864);            //  65536 B
    ushort* c4g = (ushort*)(fb + 102400);           // 131072 B
    ushort* d1g = (ushort*)(fb + 233472);           // 131072 B
    ushort* d2g = (ushort*)(fb + 364544);           //  65536 B
    ushort* d3g = (ushort*)(fb + 430080);           //  32768 B
    ushort* d4g = (ushort*)(fb + 462848);           //  16384 B
    ushort* encwTb = (ushort*)(fb + 479232);        // 384000 B [L,192,100] bf16
    ushort* fc1g  = (ushort*)(fb + 1247232);        // 393216 B [32][12][512]
    ushort* dfcg  = (ushort*)(fb + 1640448);        // 393216 B [6][64][512]
    ushort* dbf   = (ushort*)(fb + 2033664);        // 393216 B [B,192] bf16

    // ---- weight prep + x layout transform ----
    prep_all<<<3222, 256, 0, stream>>>(cw1, cw2, cw3, cw4, dw1, dw2, dw3, dw4,
                                       ein_w, fc_w, dfc_w,
                                       c1g, c2g, c3g, c4g, d1g, d2g, d3g, d4g,
                                       encwTb, fc1g, dfcg);
    nchw2nhwc<<<1024, 256, 0, stream>>>(x, xh);

    // ---- encoder ----
    conv12_fused<<<2048, 512, 0, stream>>>(xh, c1g, cb1, c2g, cb2, bufB);
    conv34_fused<<<1024, 256, 0, stream>>>(bufB, c3g, cb3, c4g, cb4, bufD);
    fc1_mfma<<<192, 256, 0, stream>>>(bufD, fc1g, fc_b, bufH);
    enc_switch4<<<256, 256, 0, stream>>>(bufH, encwTb, ein_b, eout_w, eout_b,
                                         esw_w, esw_b, gnoise, yidx, gate);
    zfcl_kernel<<<1024, 192, 0, stream>>>(bufH, mean_w, mean_b, lv_w, lv_b,
                                          znoise, fcl_w, fcl_b,
                                          z_out, zm_out, zl_out, bufD2);
    dec_switch_all<<<1024, 256, 0, stream>>>(bufD2, din_w, din_b, dout_w, dout_b,
                                             yidx, gate, dbf);
    dfc_mfma<<<256, 256, 0, stream>>>(dbf, dfcg, dfc_b, bufD);

    // ---- decoder ----
    deconv12_fused<<<1024, 256, 0, stream>>>(bufD, d1g, db1, d2g, db2, bufB);
    deconv34_fused<<<2048, 256, 0, stream>>>(bufB, d3g, db3, d4g, db4, recon);
}

// Round 25
// 221.859 us; speedup vs baseline: 1.0107x; 1.0107x over previous
//
#include <hip/hip_runtime.h>
#include <hip/hip_bf16.h>
#include <math.h>

// ---------------------------------------------------------------------------
// FCSwitchedBetaVAE forward. Conv/deconv/FC stack as implicit-GEMM on
// mfma_f32_16x16x32_bf16 (NHWC bf16 activations, f32 accum).
// x is pre-transposed NCHW f32 -> NHWC-pad4 bf16 inside prep_all (overlapped
// with weight prep; one 8B load per conv1 tap).
// Fusions: conv1+conv2 (half-image LDS, 512-thread blocks), conv3+conv4
// (full-image LDS), deconv1+deconv2 (full-image LDS), deconv3+deconv4
// (half-image LDS, kg-XOR bank swizzle, 256-thread blocks).
// B=1024, C=3, L=10, D=192, K=10, S=10.
// ---------------------------------------------------------------------------

#define BATCH 1024

using short8  = __attribute__((ext_vector_type(8))) short;
using f32x4   = __attribute__((ext_vector_type(4))) float;
using ushort4v = __attribute__((ext_vector_type(4))) ushort;

__device__ __forceinline__ ushort f2bf(float f) {
    uint u = __float_as_uint(f);
    uint r = (u + 0x7fffu + ((u >> 16) & 1u)) >> 16;   // RNE
    return (ushort)r;
}
__device__ __forceinline__ float bf2f(ushort u) {
    return __uint_as_float(((uint)u) << 16);
}

// ---------------- merged weight-fragment prep + x transform ----------------
__device__ __forceinline__ void conv_frag_elem(const float* __restrict__ w,
                                               ushort* __restrict__ frag,
                                               int idx, int CIN, int COUT) {
    int NCH = CIN / 32, NT = COUT / 16;
    int j = idx & 7; int lane = (idx >> 3) & 63; int rest = idx >> 9;
    int ntile = rest % NT; rest /= NT;
    int ch = rest % NCH; int tap = rest / NCH;
    int o = ntile * 16 + (lane & 15);
    int i = ch * 32 + (lane >> 4) * 8 + j;
    frag[idx] = f2bf(w[((size_t)(o * CIN + i)) * 16 + tap]);
}
__device__ __forceinline__ void deconv_frag_elem(const float* __restrict__ w,
                                                 ushort* __restrict__ frag,
                                                 int idx, int CIN, int COUT) {
    int NCH = CIN / 32, NT = COUT / 16;
    int j = idx & 7; int lane = (idx >> 3) & 63; int rest = idx >> 9;
    int ntile = rest % NT; rest /= NT;
    int ch = rest % NCH; rest /= NCH;
    int tapidx = rest % 4; int cls = rest / 4;
    int py = cls >> 1, px = cls & 1, a = tapidx >> 1, b = tapidx & 1;
    int tap = (py + 2 * a) * 4 + (px + 2 * b);
    int o = ntile * 16 + (lane & 15);
    int i = ch * 32 + (lane >> 4) * 8 + j;
    frag[idx] = f2bf(w[((size_t)(o * CIN + i)) * 16 + tap]);
}

__global__ __launch_bounds__(256)
void prep_all(const float* __restrict__ cw1, const float* __restrict__ cw2,
              const float* __restrict__ cw3, const float* __restrict__ cw4,
              const float* __restrict__ dw1, const float* __restrict__ dw2,
              const float* __restrict__ dw3, const float* __restrict__ dw4,
              const float* __restrict__ ein_w, const float* __restrict__ fc_w,
              const float* __restrict__ dfc_w, const float* __restrict__ x,
              ushort* __restrict__ c1g, ushort* __restrict__ c2g,
              ushort* __restrict__ c3g, ushort* __restrict__ c4g,
              ushort* __restrict__ d1g, ushort* __restrict__ d2g,
              ushort* __restrict__ d3g, ushort* __restrict__ d4g,
              ushort* __restrict__ encwTb, ushort* __restrict__ fc1g,
              ushort* __restrict__ dfcg, ushort* __restrict__ xh) {
    const int b = blockIdx.x, t = threadIdx.x;
    if (b < 8) {                    // conv1 frag: K = tap*4 + c, c=3 pad
        int idx = b * 256 + t;
        if (idx < 2048) {
            int j = idx & 7; int lane = (idx >> 3) & 63;
            int ntile = (idx >> 9) & 1; int s = idx >> 10;
            int o = ntile * 16 + (lane & 15);
            int kg = lane >> 4;
            int tap = s * 8 + kg * 2 + (j >> 2);
            int c = j & 3;
            c1g[idx] = (c < 3) ? f2bf(cw1[((size_t)(o * 3 + c)) * 16 + tap]) : (ushort)0;
        }
    } else if (b < 72) {
        conv_frag_elem(cw2, c2g, (b - 8) * 256 + t, 32, 32);
    } else if (b < 200) {
        conv_frag_elem(cw3, c3g, (b - 72) * 256 + t, 32, 64);
    } else if (b < 456) {
        conv_frag_elem(cw4, c4g, (b - 200) * 256 + t, 64, 64);
    } else if (b < 712) {
        deconv_frag_elem(dw1, d1g, (b - 456) * 256 + t, 64, 64);
    } else if (b < 840) {
        deconv_frag_elem(dw2, d2g, (b - 712) * 256 + t, 64, 32);
    } else if (b < 904) {
        deconv_frag_elem(dw3, d3g, (b - 840) * 256 + t, 32, 32);
    } else if (b < 936) {           // deconv_last frag, COUT 3 -> padded 16
        int idx = (b - 904) * 256 + t;
        if (idx < 8192) {
            int j = idx & 7; int lane = (idx >> 3) & 63; int rest = idx >> 9;
            int tapidx = rest & 3; int cls = rest >> 2;
            int py = cls >> 1, px = cls & 1, a = tapidx >> 1, bb = tapidx & 1;
            int tap = (py + 2 * a) * 4 + (px + 2 * bb);
            int o = lane & 15;
            int i = (lane >> 4) * 8 + j;
            d4g[idx] = (o < 3) ? f2bf(dw4[((size_t)(o * 32 + i)) * 16 + tap]) : (ushort)0;
        }
    } else if (b < 1686) {          // encoder winT bf16 [L,D,K*S]
        int idx = (b - 936) * 256 + t;
        if (idx < 192000) {
            int ks = idx % 100;
            int d = (idx / 100) % 192;
            int l = idx / 19200;
            int k = ks / 10, s = ks % 10;
            encwTb[idx] = f2bf(ein_w[(size_t)l * 19200 + k * 1920 + d * 10 + s]);
        }
    } else if (b < 2454) {          // fc1 frag
        int idx = (b - 1686) * 256 + t;
        int jj = idx & 7; int lane = (idx >> 3) & 63; int rest = idx >> 9;
        int nt = rest % 12, s = rest / 12;
        int k_nat = s * 32 + (lane >> 4) * 8 + jj;
        int d = (k_nat & 63) * 16 + (k_nat >> 6);
        int j = nt * 16 + (lane & 15);
        fc1g[idx] = f2bf(fc_w[(size_t)d * 192 + j]);
    } else if (b < 3222) {          // dfc frag
        int idx = (b - 2454) * 256 + t;
        int jj = idx & 7; int lane = (idx >> 3) & 63; int rest = idx >> 9;
        int nt = rest % 64, s = rest / 64;
        int k = s * 32 + (lane >> 4) * 8 + jj;
        int j_nat = nt * 16 + (lane & 15);
        int d = (j_nat & 63) * 16 + (j_nat >> 6);
        dfcg[idx] = f2bf(dfc_w[(size_t)k * 1024 + d]);
    } else {                        // b < 4246: x NCHW f32 -> NHWC-pad4 bf16
        const int n = b - 3222;
        const float* xb = x + (size_t)n * 12288;
        ushort* ob = xh + ((size_t)n << 14);
        #pragma unroll
        for (int i = 0; i < 4; ++i) {
            const int p0 = (i * 256 + t) << 2;   // 4 pixels
            const float4 v0 = *(const float4*)(xb + p0);
            const float4 v1 = *(const float4*)(xb + 4096 + p0);
            const float4 v2 = *(const float4*)(xb + 8192 + p0);
            short8 o0, o1;
            o0[0] = (short)f2bf(v0.x); o0[1] = (short)f2bf(v1.x); o0[2] = (short)f2bf(v2.x); o0[3] = 0;
            o0[4] = (short)f2bf(v0.y); o0[5] = (short)f2bf(v1.y); o0[6] = (short)f2bf(v2.y); o0[7] = 0;
            o1[0] = (short)f2bf(v0.z); o1[1] = (short)f2bf(v1.z); o1[2] = (short)f2bf(v2.z); o1[3] = 0;
            o1[4] = (short)f2bf(v0.w); o1[5] = (short)f2bf(v1.w); o1[6] = (short)f2bf(v2.w); o1[7] = 0;
            *(short8*)(ob + (size_t)(p0 << 2)) = o0;
            *(short8*)(ob + (size_t)(p0 << 2) + 8) = o1;
        }
    }
}

// ---- FUSED conv1+conv2: xh NHWC bf16 [B,64,64,4] -> bufB [B,16,16,32] -----
// B*2 blocks x 512 threads (8 waves). Phase A: conv1 rows my = 16h-1..16h+16
// into LDS mid[576][40] bf16; one 8B load per tap (4 loads/gather, 0 cvt).
// Phase B: conv2 output rows [8h, 8h+8).
__global__ __launch_bounds__(512)
void conv12_fused(const ushort* __restrict__ xh, const ushort* __restrict__ w1frag,
                  const float* __restrict__ b1, const ushort* __restrict__ w2frag,
                  const float* __restrict__ b2, ushort* __restrict__ out) {
    __shared__ ushort mid[576 * 40];   // 46080 B
    const int t = threadIdx.x;
    const int lane = t & 63, w = t >> 6;   // w in [0,8)
    const int m = lane & 15, kg = lane >> 4;
    const int h = blockIdx.x & 1, n = blockIdx.x >> 1;
    const int base = 16 * h - 1;
    const ushort* xb = xh + ((size_t)n << 14);

    short8 bf1[4];
    #pragma unroll
    for (int f = 0; f < 4; ++f)
        bf1[f] = *(const short8*)(w1frag + (f << 9) + lane * 8);

    auto gatherA = [&](int mt, short8* av) {
        const int lp = mt * 16 + m;
        const int lx = lp & 31, lyy = lp >> 5;
        const int my = base + lyy;
        const int iy0 = 2 * my - 1, ix0 = 2 * lx - 1;
        #pragma unroll
        for (int s = 0; s < 2; ++s) {
            union { ushort4v h4[2]; short8 s8; } a;
            #pragma unroll
            for (int tt = 0; tt < 2; ++tt) {
                const int tap = s * 8 + kg * 2 + tt;
                const int ky = tap >> 2, kx = tap & 3;
                const int iy = iy0 + ky, ix = ix0 + kx;
                ushort4v v = {0, 0, 0, 0};
                if ((unsigned)iy < 64u && (unsigned)ix < 64u)
                    v = *(const ushort4v*)(xb + (size_t)(((iy << 6) + ix) << 2));
                a.h4[tt] = v;
            }
            av[s] = a.s8;
        }
    };
    auto commitA = [&](int mt, short8* av) {
        f32x4 acc[2] = {{0,0,0,0},{0,0,0,0}};
        #pragma unroll
        for (int s = 0; s < 2; ++s)
            #pragma unroll
            for (int nt = 0; nt < 2; ++nt)
                acc[nt] = __builtin_amdgcn_mfma_f32_16x16x32_bf16(av[s], bf1[s * 2 + nt], acc[nt], 0, 0, 0);
        #pragma unroll
        for (int nt = 0; nt < 2; ++nt) {
            const int och = (nt << 4) + m;
            const float bv = b1[och];
            #pragma unroll
            for (int r = 0; r < 4; ++r) {
                const int lpr = (mt << 4) + (kg << 2) + r;
                mid[(size_t)lpr * 40 + och] = f2bf(fmaxf(acc[nt][r] + bv, 0.f));
            }
        }
    };

    // -------- phase A: 36 mtiles / 8 waves, 2-way unrolled -----
    {
        short8 avA[2], avB[2];
        gatherA(w, avA);
        gatherA(w + 8, avB);
        commitA(w, avA);
        commitA(w + 8, avB);
        gatherA(w + 16, avA);
        gatherA(w + 24, avB);
        commitA(w + 16, avA);
        commitA(w + 24, avB);
        if (w < 4) {
            gatherA(w + 32, avA);
            commitA(w + 32, avA);
        }
    }
    __syncthreads();
    // -------- phase B: conv2, 16 combos / 8 waves --------
    for (int it = 0; it < 2; ++it) {
        const int u = it * 8 + w;            // 0..15
        const int nt = u & 1, mt2 = u >> 1;  // mt2 0..7
        const int p2 = (mt2 << 4) + m;
        const int ox2 = p2 & 15, ly2 = p2 >> 4;
        const int oy2 = 8 * h + ly2;
        const int iy0 = 2 * oy2 - 1, ix0 = 2 * ox2 - 1;
        f32x4 acc = {0, 0, 0, 0};
        const ushort* wl = w2frag + ((size_t)nt << 9) + lane * 8;
        #pragma unroll
        for (int ky = 0; ky < 4; ++ky) {
            const int iy = iy0 + ky;
            const bool vy = (unsigned)iy < 32u;
            const int liy = iy - base;
            #pragma unroll
            for (int kx = 0; kx < 4; ++kx) {
                const int ix = ix0 + kx;
                const bool v = vy && ((unsigned)ix < 32u);
                short8 a = {0, 0, 0, 0, 0, 0, 0, 0};
                if (v) a = *(const short8*)(mid + (size_t)((liy << 5) + ix) * 40 + kg * 8);
                const short8 b = *(const short8*)(wl + ((size_t)((ky * 4 + kx) * 2) << 9));
                acc = __builtin_amdgcn_mfma_f32_16x16x32_bf16(a, b, acc, 0, 0, 0);
            }
        }
        const int och = (nt << 4) + m;
        const float bv = b2[och];
        ushort* ob = out + ((size_t)n * 256 + 128 * h + (mt2 << 4) + (kg << 2)) * 32;
        #pragma unroll
        for (int r = 0; r < 4; ++r)
            ob[r * 32 + och] = f2bf(fmaxf(acc[r] + bv, 0.f));
    }
}

// ---- FUSED conv3+conv4: bufB [B,16,16,32] -> bufD [B*16][64] --------------
__global__ __launch_bounds__(256)
void conv34_fused(const ushort* __restrict__ in, const ushort* __restrict__ w3frag,
                  const float* __restrict__ b3, const ushort* __restrict__ w4frag,
                  const float* __restrict__ b4, ushort* __restrict__ out) {
    __shared__ ushort mid[64 * 64];   // 8192 B
    const int t = threadIdx.x;
    const int lane = t & 63, w = t >> 6;
    const int m = lane & 15, kg = lane >> 4;
    const int n = blockIdx.x;
    const ushort* ibase = in + ((size_t)n << 13);   // 16*16*32

    // -------- phase A: conv3 (CIN=32,COUT=64,HIN=16) --------
    {
        const int p = (w << 4) + m;          // pixel 0..63
        const int ox = p & 7, oy = p >> 3;
        const int iy0 = 2 * oy - 1, ix0 = 2 * ox - 1;
        f32x4 acc[4] = {{0,0,0,0},{0,0,0,0},{0,0,0,0},{0,0,0,0}};
        #pragma unroll
        for (int ky = 0; ky < 4; ++ky) {
            const int iy = iy0 + ky;
            const bool vy = (unsigned)iy < 16u;
            #pragma unroll
            for (int kx = 0; kx < 4; ++kx) {
                const int ix = ix0 + kx;
                const bool v = vy && ((unsigned)ix < 16u);
                short8 a = {0, 0, 0, 0, 0, 0, 0, 0};
                if (v) a = *(const short8*)(ibase + (size_t)((iy << 4) + ix) * 32 + kg * 8);
                const int tap = ky * 4 + kx;
                #pragma unroll
                for (int nt = 0; nt < 4; ++nt) {
                    const short8 b = *(const short8*)(w3frag + ((size_t)(tap * 4 + nt) << 9) + lane * 8);
                    acc[nt] = __builtin_amdgcn_mfma_f32_16x16x32_bf16(a, b, acc[nt], 0, 0, 0);
                }
            }
        }
        #pragma unroll
        for (int nt = 0; nt < 4; ++nt) {
            const int och = (nt << 4) + m;
            const float bv = b3[och];
            #pragma unroll
            for (int r = 0; r < 4; ++r) {
                const int pr = (w << 4) + (kg << 2) + r;
                mid[(size_t)pr * 64 + och] = f2bf(fmaxf(acc[nt][r] + bv, 0.f));
            }
        }
    }
    __syncthreads();
    // -------- phase B: conv4 (CIN=64,COUT=64,HIN=8), wave = ntile --------
    {
        const int ox = m & 3, oy = m >> 2;
        const int iy0 = 2 * oy - 1, ix0 = 2 * ox - 1;
        f32x4 acc = {0, 0, 0, 0};
        const ushort* wl = w4frag + ((size_t)w << 9) + lane * 8;
        #pragma unroll
        for (int ky = 0; ky < 4; ++ky) {
            const int iy = iy0 + ky;
            const bool vy = (unsigned)iy < 8u;
            #pragma unroll
            for (int kx = 0; kx < 4; ++kx) {
                const int ix = ix0 + kx;
                const bool v = vy && ((unsigned)ix < 8u);
                const int tap = ky * 4 + kx;
                #pragma unroll
                for (int ch = 0; ch < 2; ++ch) {
                    short8 a = {0, 0, 0, 0, 0, 0, 0, 0};
                    if (v) a = *(const short8*)(mid + (size_t)((iy << 3) + ix) * 64 + ch * 32 + kg * 8);
                    const short8 b = *(const short8*)(wl + ((size_t)((tap * 2 + ch) * 4) << 9));
                    acc = __builtin_amdgcn_mfma_f32_16x16x32_bf16(a, b, acc, 0, 0, 0);
                }
            }
        }
        const int och = (w << 4) + m;
        const float bv = b4[och];
        #pragma unroll
        for (int r = 0; r < 4; ++r)
            out[((size_t)n * 16 + (kg << 2) + r) * 64 + och] = f2bf(fmaxf(acc[r] + bv, 0.f));
    }
}

// ---- FUSED deconv1+deconv2: bufD [B][4,4,64] -> bufB [B,16,16,32] ---------
__global__ __launch_bounds__(256)
void deconv12_fused(const ushort* __restrict__ in, const ushort* __restrict__ w1frag,
                    const float* __restrict__ b1, const ushort* __restrict__ w2frag,
                    const float* __restrict__ b2, ushort* __restrict__ out) {
    __shared__ ushort mid[64 * 64];   // 8192 B
    const int t = threadIdx.x;
    const int lane = t & 63, w = t >> 6;
    const int m = lane & 15, kg = lane >> 4;
    const int n = blockIdx.x;
    const ushort* ibase = in + ((size_t)n << 10);   // 4*4*64

    // -------- phase A: deconv1 (CIN=64,COUT=64,HIN=4), wave = ntile --------
    {
        const int oxh = m & 3, oyh = m >> 2;
        f32x4 acc[4] = {{0,0,0,0},{0,0,0,0},{0,0,0,0},{0,0,0,0}};
        const ushort* wl = w1frag + ((size_t)w << 9) + lane * 8;
        #pragma unroll
        for (int ch = 0; ch < 2; ++ch) {
            short8 nb[3][3];
            #pragma unroll
            for (int dy = 0; dy < 3; ++dy) {
                const int iy = oyh + dy - 1;
                const bool vy = (unsigned)iy < 4u;
                #pragma unroll
                for (int dx = 0; dx < 3; ++dx) {
                    const int ix = oxh + dx - 1;
                    short8 a = {0, 0, 0, 0, 0, 0, 0, 0};
                    if (vy && (unsigned)ix < 4u)
                        a = *(const short8*)(ibase + (size_t)((iy << 2) + ix) * 64 + ch * 32 + kg * 8);
                    nb[dy][dx] = a;
                }
            }
            #pragma unroll
            for (int cls = 0; cls < 4; ++cls) {
                const int py = cls >> 1, px = cls & 1;
                #pragma unroll
                for (int ti = 0; ti < 4; ++ti) {
                    const int a2 = ti >> 1, b2i = ti & 1;
                    const short8 b = *(const short8*)(wl + ((size_t)(((cls * 4 + ti) * 2 + ch) * 4) << 9));
                    acc[cls] = __builtin_amdgcn_mfma_f32_16x16x32_bf16(nb[py + a2][px + b2i], b, acc[cls], 0, 0, 0);
                }
            }
        }
        const int och = (w << 4) + m;
        const float bv = b1[och];
        #pragma unroll
        for (int cls = 0; cls < 4; ++cls) {
            const int py = cls >> 1, px = cls & 1;
            #pragma unroll
            for (int r = 0; r < 4; ++r) {
                const int qq = (kg << 2) + r;
                const int oxh2 = qq & 3, oyh2 = qq >> 2;
                const int oy = 2 * oyh2 + py, ox = 2 * oxh2 + px;
                mid[(size_t)((oy << 3) + ox) * 64 + och] = f2bf(fmaxf(acc[cls][r] + bv, 0.f));
            }
        }
    }
    __syncthreads();
    // -------- phase B: deconv2 (CIN=64,COUT=32,HIN=8), 8 combos / 4 waves --
    for (int u = w; u < 8; u += 4) {
        const int nt = u & 1, mt = u >> 1;
        const int q = (mt << 4) + m;
        const int oxh = q & 7, oyh = q >> 3;
        f32x4 acc[4] = {{0,0,0,0},{0,0,0,0},{0,0,0,0},{0,0,0,0}};
        const ushort* wl = w2frag + ((size_t)nt << 9) + lane * 8;
        #pragma unroll
        for (int ch = 0; ch < 2; ++ch) {
            short8 nb[3][3];
            #pragma unroll
            for (int dy = 0; dy < 3; ++dy) {
                const int iy = oyh + dy - 1;
                const bool vy = (unsigned)iy < 8u;
                #pragma unroll
                for (int dx = 0; dx < 3; ++dx) {
                    const int ix = oxh + dx - 1;
                    short8 a = {0, 0, 0, 0, 0, 0, 0, 0};
                    if (vy && (unsigned)ix < 8u)
                        a = *(const short8*)(mid + (size_t)((iy << 3) + ix) * 64 + ch * 32 + kg * 8);
                    nb[dy][dx] = a;
                }
            }
            #pragma unroll
            for (int cls = 0; cls < 4; ++cls) {
                const int py = cls >> 1, px = cls & 1;
                #pragma unroll
                for (int ti = 0; ti < 4; ++ti) {
                    const int a2 = ti >> 1, b2i = ti & 1;
                    const short8 b = *(const short8*)(wl + ((size_t)(((cls * 4 + ti) * 2 + ch) * 2) << 9));
                    acc[cls] = __builtin_amdgcn_mfma_f32_16x16x32_bf16(nb[py + a2][px + b2i], b, acc[cls], 0, 0, 0);
                }
            }
        }
        const int och = (nt << 4) + m;
        const float bv = b2[och];
        #pragma unroll
        for (int cls = 0; cls < 4; ++cls) {
            const int py = cls >> 1, px = cls & 1;
            #pragma unroll
            for (int r = 0; r < 4; ++r) {
                const int qq = (mt << 4) + (kg << 2) + r;
                const int oxh2 = qq & 7, oyh2 = qq >> 3;
                const int oy = 2 * oyh2 + py, ox = 2 * oxh2 + px;
                out[((size_t)(n * 16 + oy) * 16 + ox) * 32 + och] = f2bf(fmaxf(acc[cls][r] + bv, 0.f));
            }
        }
    }
}

// ---- FUSED deconv3+deconv4: bufB [B,16,16,32] -> recon NCHW f32 [B,3,64,64]
// B*2 blocks x 256 threads. mid uses kg-XOR channel swizzle: writer kg ==
// (pix>>3)&3, stored at och ^ (kg<<3); reader recovers (kg ^ ((ix>>3)&3))*8.
__global__ __launch_bounds__(256)
void deconv34_fused(const ushort* __restrict__ in, const ushort* __restrict__ w3frag,
                    const float* __restrict__ b3, const ushort* __restrict__ w4frag,
                    const float* __restrict__ b4, float* __restrict__ out) {
    __shared__ ushort mid[20 * 32 * 32];   // 40960 B
    const int t = threadIdx.x;
    const int lane = t & 63, w = t >> 6;
    const int m = lane & 15, kg = lane >> 4;
    const int h = blockIdx.x & 1, n = blockIdx.x >> 1;
    const int base = 16 * h - 2;
    const ushort* ibase = in + ((size_t)n << 13);   // 16*16*32

    // -------- phase A: deconv3 rows ir = 8h-1 .. 8h+8 --> mid --------
    for (int u = w; u < 20; u += 4) {
        const int nt = u & 1, mt = u >> 1;
        const int ir = 8 * h - 1 + mt;
        short8 nb[3][3];
        #pragma unroll
        for (int dy = 0; dy < 3; ++dy) {
            const int iy = ir + dy - 1;
            const bool vy = (unsigned)iy < 16u;
            #pragma unroll
            for (int dx = 0; dx < 3; ++dx) {
                const int ix = m + dx - 1;
                short8 a = {0, 0, 0, 0, 0, 0, 0, 0};
                if (vy && (unsigned)ix < 16u)
                    a = *(const short8*)(ibase + (size_t)((iy << 4) + ix) * 32 + kg * 8);
                nb[dy][dx] = a;
            }
        }
        const ushort* wl = w3frag + ((size_t)nt << 9) + lane * 8;
        f32x4 acc[4] = {{0,0,0,0},{0,0,0,0},{0,0,0,0},{0,0,0,0}};
        #pragma unroll
        for (int cls = 0; cls < 4; ++cls) {
            const int py = cls >> 1, px = cls & 1;
            #pragma unroll
            for (int ti = 0; ti < 4; ++ti) {
                const int a2 = ti >> 1, b2 = ti & 1;
                const short8 b = *(const short8*)(wl + ((size_t)((cls * 4 + ti) * 2) << 9));
                acc[cls] = __builtin_amdgcn_mfma_f32_16x16x32_bf16(nb[py + a2][px + b2], b, acc[cls], 0, 0, 0);
            }
        }
        const int och = (nt << 4) + m;
        const int ochSw = och ^ (kg << 3);   // bank swizzle (writer kg)
        const float bv = b3[och];
        #pragma unroll
        for (int cls = 0; cls < 4; ++cls) {
            const int py = cls >> 1, px = cls & 1;
            const int ly = 2 * mt + py;
            #pragma unroll
            for (int r = 0; r < 4; ++r) {
                const int ox = ((kg << 3) + 2 * r) + px;
                mid[(size_t)((ly << 5) + ox) * 32 + ochSw] = f2bf(fmaxf(acc[cls][r] + bv, 0.f));
            }
        }
    }
    __syncthreads();
    // -------- phase B: deconv_last, output rows [32h, 32h+32) --------
    for (int it = 0; it < 8; ++it) {
        const int mt2 = it * 4 + w;
        const int oyh = 16 * h + (mt2 >> 1);
        const int oxh = ((mt2 & 1) << 4) + m;
        short8 nb[3][3];
        #pragma unroll
        for (int dy = 0; dy < 3; ++dy) {
            const int iy = oyh + dy - 1;
            const bool vy = (unsigned)iy < 32u;
            const int ly = iy - base;
            #pragma unroll
            for (int dx = 0; dx < 3; ++dx) {
                const int ix = oxh + dx - 1;
                short8 a = {0, 0, 0, 0, 0, 0, 0, 0};
                if (vy && (unsigned)ix < 32u) {
                    const int rb = (kg ^ ((ix >> 3) & 3)) << 3;   // un-swizzle
                    a = *(const short8*)(mid + (size_t)((ly << 5) + ix) * 32 + rb);
                }
                nb[dy][dx] = a;
            }
        }
        f32x4 acc[4] = {{0,0,0,0},{0,0,0,0},{0,0,0,0},{0,0,0,0}};
        const ushort* wl = w4frag + lane * 8;
        #pragma unroll
        for (int cls = 0; cls < 4; ++cls) {
            const int py = cls >> 1, px = cls & 1;
            #pragma unroll
            for (int ti = 0; ti < 4; ++ti) {
                const int a2 = ti >> 1, b2 = ti & 1;
                const short8 b = *(const short8*)(wl + ((cls * 4 + ti) << 9));
                acc[cls] = __builtin_amdgcn_mfma_f32_16x16x32_bf16(nb[py + a2][px + b2], b, acc[cls], 0, 0, 0);
            }
        }
        if (m < 3) {
            const float bv = b4[m];
            float* ob = out + (size_t)n * 12288 + m * 4096;
            #pragma unroll
            for (int r = 0; r < 4; ++r) {
                const int x = ((mt2 & 1) << 4) + (kg << 2) + r;
                #pragma unroll
                for (int py = 0; py < 2; ++py) {
                    float2 v = {acc[py * 2 + 0][r] + bv, acc[py * 2 + 1][r] + bv};
                    *(float2*)(ob + (2 * oyh + py) * 64 + 2 * x) = v;
                }
            }
        }
    }
}

// ---------------- fc1 MFMA: bufD [B,1024] bf16 -> bufH [B,192] f32 ---------
__global__ __launch_bounds__(256)
void fc1_mfma(const ushort* __restrict__ in, const ushort* __restrict__ frag,
              const float* __restrict__ bias, float* __restrict__ out) {
    const int lane = threadIdx.x & 63;
    const int gw = (blockIdx.x << 2) + (threadIdx.x >> 6);   // [0,768)
    const int nt = gw % 12, mt = gw / 12;
    const int m = lane & 15, kg = lane >> 4;
    const ushort* arow = in + ((size_t)(mt * 16 + m) << 10) + kg * 8;
    const ushort* wl = frag + nt * 512 + lane * 8;
    f32x4 acc0 = {0, 0, 0, 0}, acc1 = {0, 0, 0, 0};
    #pragma unroll
    for (int s = 0; s < 32; s += 2) {
        const short8 a0 = *(const short8*)(arow + s * 32);
        const short8 a1 = *(const short8*)(arow + s * 32 + 32);
        const short8 b0 = *(const short8*)(wl + ((size_t)(s * 12) << 9));
        const short8 b1 = *(const short8*)(wl + ((size_t)((s + 1) * 12) << 9));
        acc0 = __builtin_amdgcn_mfma_f32_16x16x32_bf16(a0, b0, acc0, 0, 0, 0);
        acc1 = __builtin_amdgcn_mfma_f32_16x16x32_bf16(a1, b1, acc1, 0, 0, 0);
    }
    const int j = nt * 16 + m;
    const float bv = bias[j];
    #pragma unroll
    for (int r = 0; r < 4; ++r)
        out[(size_t)(mt * 16 + kg * 4 + r) * 192 + j] = (acc0[r] + acc1[r]) + bv;
}

// --------- dfc MFMA: dbf [B,192] bf16 -> bufD [B,1024] bf16 (NHWC), relu ---
__global__ __launch_bounds__(256)
void dfc_mfma(const ushort* __restrict__ in, const ushort* __restrict__ frag,
              const float* __restrict__ bias, ushort* __restrict__ out) {
    const int lane = threadIdx.x & 63;
    const int gw = (blockIdx.x << 2) + (threadIdx.x >> 6);   // [0,1024)
    const int ntg = gw & 15, mt = gw >> 4;
    const int m = lane & 15, kg = lane >> 4;
    const ushort* arow = in + (size_t)(mt * 16 + m) * 192 + kg * 8;
    const ushort* wl = frag + ((size_t)(ntg * 4) << 9) + lane * 8;
    f32x4 acc[4] = {{0,0,0,0},{0,0,0,0},{0,0,0,0},{0,0,0,0}};
    #pragma unroll
    for (int s = 0; s < 6; ++s) {
        const short8 a = *(const short8*)(arow + s * 32);
        #pragma unroll
        for (int q = 0; q < 4; ++q) {
            const short8 b = *(const short8*)(wl + ((size_t)(s * 64 + q) << 9));
            acc[q] = __builtin_amdgcn_mfma_f32_16x16x32_bf16(a, b, acc[q], 0, 0, 0);
        }
    }
    #pragma unroll
    for (int q = 0; q < 4; ++q) {
        const int j_nat = (ntg * 4 + q) * 16 + m;
        const int d = (j_nat & 63) * 16 + (j_nat >> 6);
        const float bv = bias[d];
        #pragma unroll
        for (int r = 0; r < 4; ++r) {
            const float vv = fmaxf(acc[q][r] + bv, 0.f);
            out[((size_t)(mt * 16 + kg * 4 + r) << 10) + j_nat] = f2bf(vv);
        }
    }
}

// ---- encoder switch chain: 4 rows/block, bf16 winT, ILP-4 VALU hid --------
__global__ __launch_bounds__(256)
void enc_switch4(float* __restrict__ h,
                 const ushort* __restrict__ winTb,   // [L,192,100] bf16
                 const float* __restrict__ bin_all,  // [L,100]
                 const float* __restrict__ wout_all, // [L,K,10,192]
                 const float* __restrict__ bout_all, // [L,K,192]
                 const float* __restrict__ wsw_all,  // [L,K,10]
                 const float* __restrict__ bsw_all,  // [L,K]
                 const float* __restrict__ gn_all,   // [L,B,10]
                 int* __restrict__ yidx, float* __restrict__ gateArr) {
    const int t = threadIdx.x;
    const int b0 = blockIdx.x << 2;
    __shared__ float hold[4][192], r[4][192], part[4][200], hid[4][100], lg[4][10];
    __shared__ int yi_s[4]; __shared__ float gate_s[4];
    if (t < 192) {
        #pragma unroll
        for (int row = 0; row < 4; ++row) {
            const float v = h[(size_t)(b0 + row) * 192 + t];
            hold[row][t] = v; r[row][t] = fmaxf(v, 0.f);
        }
    }
    for (int i = 0; i < 10; ++i) {
        __syncthreads();   // r ready
        if (t < 200) {
            const int ks = (t < 100) ? t : t - 100;
            const int half = (t < 100) ? 0 : 1;
            const ushort* wp = winTb + (size_t)i * 19200 + (half * 96) * 100 + ks;
            const float* r0 = &r[0][half * 96];
            const float* r1 = &r[1][half * 96];
            const float* r2 = &r[2][half * 96];
            const float* r3 = &r[3][half * 96];
            float a0 = 0.f, a1 = 0.f, a2 = 0.f, a3 = 0.f;
            #pragma unroll
            for (int dd = 0; dd < 96; ++dd) {
                const float wv = bf2f(wp[dd * 100]);
                a0 = fmaf(r0[dd], wv, a0);
                a1 = fmaf(r1[dd], wv, a1);
                a2 = fmaf(r2[dd], wv, a2);
                a3 = fmaf(r3[dd], wv, a3);
            }
            part[0][t] = a0; part[1][t] = a1; part[2][t] = a2; part[3][t] = a3;
        }
        __syncthreads();
        if (t < 100) {
            const float bv = bin_all[i * 100 + t];
            #pragma unroll
            for (int row = 0; row < 4; ++row)
                hid[row][t] = part[row][t] + part[row][t + 100] + bv;
        }
        __syncthreads();
        if (t < 40) {
            const int row = t / 10, k = t % 10;
            const float* wsw = wsw_all + i * 100 + k * 10;
            float acc = bsw_all[i * 10 + k];
            #pragma unroll
            for (int s = 0; s < 10; ++s) acc = fmaf(hid[row][k * 10 + s], wsw[s], acc);
            lg[row][k] = acc - logf(gn_all[(size_t)i * 10240 + (b0 + row) * 10 + k] + 1e-20f);
        }
        __syncthreads();
        if (t < 4) {
            int bi = 0; float best = lg[t][0];
            #pragma unroll
            for (int k = 1; k < 10; ++k) if (lg[t][k] > best) { best = lg[t][k]; bi = k; }
            float sum = 0.f;
            #pragma unroll
            for (int k = 0; k < 10; ++k) sum += expf(lg[t][k] - best);
            const float ysoft = 1.0f / sum;
            yi_s[t] = bi;
            const float g = (1.0f - ysoft) + ysoft;
            gate_s[t] = g;
            yidx[i * 1024 + b0 + t] = bi;
            gateArr[i * 1024 + b0 + t] = g;
        }
        __syncthreads();
        if (t < 192) {
            #pragma unroll
            for (int row = 0; row < 4; ++row) {
                const int yi = yi_s[row];
                const float gate = gate_s[row];
                const float* wb = wout_all + (size_t)i * 19200 + yi * 1920 + t;
                float acc = bout_all[i * 1920 + yi * 192 + t];
                #pragma unroll
                for (int s = 0; s < 10; ++s) acc = fmaf(hid[row][yi * 10 + s], wb[s * 192], acc);
                const float nv = hold[row][t] + acc * gate;
                hold[row][t] = nv; r[row][t] = fmaxf(nv, 0.f);
            }
        }
    }
    __syncthreads();
    if (t < 192) {
        #pragma unroll
        for (int row = 0; row < 4; ++row)
            h[(size_t)(b0 + row) * 192 + t] = hold[row][t];
    }
}

// ------- fused decoder switch chain; emits bf16 relu'd state for dfc -------
__global__ __launch_bounds__(256)
void dec_switch_all(const float* __restrict__ h,
                    const float* __restrict__ win_all,   // [L,K,192,10]
                    const float* __restrict__ bin_all,   // [L,K,10]
                    const float* __restrict__ wout_all,  // [L,K,10,192]
                    const float* __restrict__ bout_all,  // [L,K,192]
                    const int* __restrict__ yidx, const float* __restrict__ gateArr,
                    ushort* __restrict__ dbf) {
    const int b = blockIdx.x, t = threadIdx.x;
    __shared__ float hold[192], r[192], part[240], hid[10];
    if (t < 192) { float v = h[(size_t)b * 192 + t]; hold[t] = v; r[t] = fmaxf(v, 0.f); }
    for (int i = 0; i < 10; ++i) {
        const int yi = yidx[i * 1024 + b];
        const float gate = gateArr[i * 1024 + b];
        __syncthreads();   // r ready
        if (t < 240) {
            const int s = t % 10, g = t / 10;     // 24 groups x 8 d's
            const float* wp = win_all + (size_t)i * 19200 + yi * 1920 + s;
            const int d0 = g * 8;
            float a0 = 0.f, a1 = 0.f;
            #pragma unroll
            for (int dd = 0; dd < 8; dd += 2) {
                a0 = fmaf(r[d0 + dd + 0], wp[(d0 + dd + 0) * 10], a0);
                a1 = fmaf(r[d0 + dd + 1], wp[(d0 + dd + 1) * 10], a1);
            }
            part[t] = a0 + a1;
        }
        __syncthreads();
        if (t < 10) {
            float acc = bin_all[i * 100 + yi * 10 + t];
            #pragma unroll
            for (int g = 0; g < 24; ++g) acc += part[g * 10 + t];
            hid[t] = acc;
        }
        __syncthreads();
        if (t < 192) {
            const float* wp = wout_all + (size_t)i * 19200 + yi * 1920 + t;
            float acc = bout_all[i * 1920 + yi * 192 + t];
            #pragma unroll
            for (int s = 0; s < 10; ++s) acc = fmaf(hid[s], wp[s * 192], acc);
            float nv = hold[t] + acc * gate;
            hold[t] = nv; r[t] = fmaxf(nv, 0.f);
        }
    }
    if (t < 192) dbf[(size_t)b * 192 + t] = f2bf(r[t]);
}

// ------- z stats + reparameterize + decoder input FC -----------------------
__global__ __launch_bounds__(192)
void zfcl_kernel(const float* __restrict__ h,
                 const float* __restrict__ mw, const float* __restrict__ mb,
                 const float* __restrict__ lw, const float* __restrict__ lb,
                 const float* __restrict__ zn,
                 const float* __restrict__ fw, const float* __restrict__ fb,
                 float* __restrict__ out_z, float* __restrict__ out_mean,
                 float* __restrict__ out_lv, float* __restrict__ dbuf) {
    const int b = blockIdx.x, t = threadIdx.x;
    __shared__ float r[192], pm[160], pl[160], zsh[10];
    for (int d = t; d < 192; d += 192) r[d] = fmaxf(h[(size_t)b * 192 + d], 0.f);
    __syncthreads();
    if (t < 160) {
        const int l = t % 10, g = t / 10;
        float am = 0.f, al = 0.f;
        #pragma unroll
        for (int d = g * 12; d < g * 12 + 12; ++d) {
            am = fmaf(r[d], mw[d * 10 + l], am);
            al = fmaf(r[d], lw[d * 10 + l], al);
        }
        pm[t] = am; pl[t] = al;
    }
    __syncthreads();
    if (t < 10) {
        float zm = mb[t], zl = lb[t];
        #pragma unroll
        for (int g = 0; g < 16; ++g) { zm += pm[g * 10 + t]; zl += pl[g * 10 + t]; }
        const float z = zn[(size_t)b * 10 + t] * expf(zl * 0.5f) + zm;
        out_mean[(size_t)b * 10 + t] = zm;
        out_lv[(size_t)b * 10 + t] = zl;
        out_z[(size_t)b * 10 + t] = z;
        zsh[t] = z;
    }
    __syncthreads();
    for (int d = t; d < 192; d += 192) {
        float acc = fb[d];
        #pragma unroll
        for (int l = 0; l < 10; ++l) acc = fmaf(zsh[l], fw[l * 192 + d], acc);
        dbuf[(size_t)b * 192 + d] = acc;
    }
}

// ---------------------------------------------------------------------------
extern "C" void kernel_launch(void* const* d_in, const int* in_sizes, int n_in,
                              void* d_out, int out_size, void* d_ws, size_t ws_size,
                              hipStream_t stream) {
    const float* x      = (const float*)d_in[0];
    const float* gnoise = (const float*)d_in[1];
    const float* znoise = (const float*)d_in[2];
    const float* cw1 = (const float*)d_in[3];  const float* cb1 = (const float*)d_in[4];
    const float* cw2 = (const float*)d_in[5];  const float* cb2 = (const float*)d_in[6];
    const float* cw3 = (const float*)d_in[7];  const float* cb3 = (const float*)d_in[8];
    const float* cw4 = (const float*)d_in[9];  const float* cb4 = (const float*)d_in[10];
    const float* fc_w = (const float*)d_in[11]; const float* fc_b = (const float*)d_in[12];
    const float* ein_w = (const float*)d_in[13]; const float* ein_b = (const float*)d_in[14];
    const float* eout_w = (const float*)d_in[15]; const float* eout_b = (const float*)d_in[16];
    const float* esw_w = (const float*)d_in[17]; const float* esw_b = (const float*)d_in[18];
    const float* mean_w = (const float*)d_in[19]; const float* mean_b = (const float*)d_in[20];
    const float* lv_w = (const float*)d_in[21]; const float* lv_b = (const float*)d_in[22];
    const float* fcl_w = (const float*)d_in[23]; const float* fcl_b = (const float*)d_in[24];
    const float* din_w = (const float*)d_in[25]; const float* din_b = (const float*)d_in[26];
    const float* dout_w = (const float*)d_in[27]; const float* dout_b = (const float*)d_in[28];
    const float* dfc_w = (const float*)d_in[29]; const float* dfc_b = (const float*)d_in[30];
    const float* dw1 = (const float*)d_in[31]; const float* db1 = (const float*)d_in[32];
    const float* dw2 = (const float*)d_in[33]; const float* db2 = (const float*)d_in[34];
    const float* dw3 = (const float*)d_in[35]; const float* db3 = (const float*)d_in[36];
    const float* dw4 = (const float*)d_in[37]; const float* db4 = (const float*)d_in[38];

    float* out = (float*)d_out;
    float* recon  = out;
    float* z_out  = out + 12582912;
    float* zm_out = z_out + 10240;
    float* zl_out = zm_out + 10240;

    char* ws = (char*)d_ws;
    ushort* xh    = (ushort*)(ws);                  // [B,64,64,4] bf16 33.6 MB
    ushort* bufB  = (ushort*)(ws + 100663296);      // [B,16,16,32] 16.8 MB
    ushort* bufD  = (ushort*)(ws + 125829120);      // [B*16][64]   2.1 MB
    float*  bufH  = (float*) (ws + 127926272);      // [B,192]
    float*  bufD2 = (float*) (ws + 128712704);      // [B,192]
    int*    yidx  = (int*)   (ws + 129499136);
    float*  gate  = (float*) (ws + 129540096);
    char*   fb    = ws + 129581056;
    ushort* c1g = (ushort*)(fb);                    //   4096 B
    ushort* c2g = (ushort*)(fb + 4096);             //  32768 B
    ushort* c3g = (ushort*)(fb + 36864);            //  65536 B
    ushort* c4g = (ushort*)(fb + 102400);           // 131072 B
    ushort* d1g = (ushort*)(fb + 233472);           // 131072 B
    ushort* d2g = (ushort*)(fb + 364544);           //  65536 B
    ushort* d3g = (ushort*)(fb + 430080);           //  32768 B
    ushort* d4g = (ushort*)(fb + 462848);           //  16384 B
    ushort* encwTb = (ushort*)(fb + 479232);        // 384000 B [L,192,100] bf16
    ushort* fc1g  = (ushort*)(fb + 1247232);        // 393216 B [32][12][512]
    ushort* dfcg  = (ushort*)(fb + 1640448);        // 393216 B [6][64][512]
    ushort* dbf   = (ushort*)(fb + 2033664);        // 393216 B [B,192] bf16

    // ---- weight prep + x layout transform (one dispatch, overlapped) ----
    prep_all<<<4246, 256, 0, stream>>>(cw1, cw2, cw3, cw4, dw1, dw2, dw3, dw4,
                                       ein_w, fc_w, dfc_w, x,
                                       c1g, c2g, c3g, c4g, d1g, d2g, d3g, d4g,
                                       encwTb, fc1g, dfcg, xh);

    // ---- encoder ----
    conv12_fused<<<2048, 512, 0, stream>>>(xh, c1g, cb1, c2g, cb2, bufB);
    conv34_fused<<<1024, 256, 0, stream>>>(bufB, c3g, cb3, c4g, cb4, bufD);
    fc1_mfma<<<192, 256, 0, stream>>>(bufD, fc1g, fc_b, bufH);
    enc_switch4<<<256, 256, 0, stream>>>(bufH, encwTb, ein_b, eout_w, eout_b,
                                         esw_w, esw_b, gnoise, yidx, gate);
    zfcl_kernel<<<1024, 192, 0, stream>>>(bufH, mean_w, mean_b, lv_w, lv_b,
                                          znoise, fcl_w, fcl_b,
                                          z_out, zm_out, zl_out, bufD2);
    dec_switch_all<<<1024, 256, 0, stream>>>(bufD2, din_w, din_b, dout_w, dout_b,
                                             yidx, gate, dbf);
    dfc_mfma<<<256, 256, 0, stream>>>(dbf, dfcg, dfc_b, bufD);

    // ---- decoder ----
    deconv12_fused<<<1024, 256, 0, stream>>>(bufD, d1g, db1, d2g, db2, bufB);
    deconv34_fused<<<2048, 256, 0, stream>>>(bufB, d3g, db3, d4g, db4, recon);
}

// Round 26
// 220.068 us; speedup vs baseline: 1.0190x; 1.0081x over previous
//
#include <hip/hip_runtime.h>
#include <hip/hip_bf16.h>
#include <math.h>

// ---------------------------------------------------------------------------
// FCSwitchedBetaVAE forward. Conv/deconv/FC stack as implicit-GEMM on
// mfma_f32_16x16x32_bf16 (NHWC bf16 activations, f32 accum).
// x is pre-transposed NCHW f32 -> NHWC-pad4 bf16 inside prep_all (overlapped
// with weight prep; one 8B load per conv1 tap).
// Fusions: conv1+conv2 (half-image LDS, 512-thread blocks), conv3+conv4
// (full-image LDS), deconv1+deconv2 (full-image LDS), deconv3+deconv4
// (half-image LDS, kg-XOR bank swizzle; deconv4 via 9-neighbor packed-N
// MFMA: N columns = (cls,och), 9 MFMAs replace 16).
// B=1024, C=3, L=10, D=192, K=10, S=10.
// ---------------------------------------------------------------------------

#define BATCH 1024

using short8  = __attribute__((ext_vector_type(8))) short;
using f32x4   = __attribute__((ext_vector_type(4))) float;
using ushort4v = __attribute__((ext_vector_type(4))) ushort;

__device__ __forceinline__ ushort f2bf(float f) {
    uint u = __float_as_uint(f);
    uint r = (u + 0x7fffu + ((u >> 16) & 1u)) >> 16;   // RNE
    return (ushort)r;
}
__device__ __forceinline__ float bf2f(ushort u) {
    return __uint_as_float(((uint)u) << 16);
}

// ---------------- merged weight-fragment prep + x transform ----------------
__device__ __forceinline__ void conv_frag_elem(const float* __restrict__ w,
                                               ushort* __restrict__ frag,
                                               int idx, int CIN, int COUT) {
    int NCH = CIN / 32, NT = COUT / 16;
    int j = idx & 7; int lane = (idx >> 3) & 63; int rest = idx >> 9;
    int ntile = rest % NT; rest /= NT;
    int ch = rest % NCH; int tap = rest / NCH;
    int o = ntile * 16 + (lane & 15);
    int i = ch * 32 + (lane >> 4) * 8 + j;
    frag[idx] = f2bf(w[((size_t)(o * CIN + i)) * 16 + tap]);
}
__device__ __forceinline__ void deconv_frag_elem(const float* __restrict__ w,
                                                 ushort* __restrict__ frag,
                                                 int idx, int CIN, int COUT) {
    int NCH = CIN / 32, NT = COUT / 16;
    int j = idx & 7; int lane = (idx >> 3) & 63; int rest = idx >> 9;
    int ntile = rest % NT; rest /= NT;
    int ch = rest % NCH; rest /= NCH;
    int tapidx = rest % 4; int cls = rest / 4;
    int py = cls >> 1, px = cls & 1, a = tapidx >> 1, b = tapidx & 1;
    int tap = (py + 2 * a) * 4 + (px + 2 * b);
    int o = ntile * 16 + (lane & 15);
    int i = ch * 32 + (lane >> 4) * 8 + j;
    frag[idx] = f2bf(w[((size_t)(o * CIN + i)) * 16 + tap]);
}

__global__ __launch_bounds__(256)
void prep_all(const float* __restrict__ cw1, const float* __restrict__ cw2,
              const float* __restrict__ cw3, const float* __restrict__ cw4,
              const float* __restrict__ dw1, const float* __restrict__ dw2,
              const float* __restrict__ dw3, const float* __restrict__ dw4,
              const float* __restrict__ ein_w, const float* __restrict__ fc_w,
              const float* __restrict__ dfc_w, const float* __restrict__ x,
              ushort* __restrict__ c1g, ushort* __restrict__ c2g,
              ushort* __restrict__ c3g, ushort* __restrict__ c4g,
              ushort* __restrict__ d1g, ushort* __restrict__ d2g,
              ushort* __restrict__ d3g, ushort* __restrict__ d4g,
              ushort* __restrict__ encwTb, ushort* __restrict__ fc1g,
              ushort* __restrict__ dfcg, ushort* __restrict__ xh) {
    const int b = blockIdx.x, t = threadIdx.x;
    if (b < 8) {                    // conv1 frag: K = tap*4 + c, c=3 pad
        int idx = b * 256 + t;
        if (idx < 2048) {
            int j = idx & 7; int lane = (idx >> 3) & 63;
            int ntile = (idx >> 9) & 1; int s = idx >> 10;
            int o = ntile * 16 + (lane & 15);
            int kg = lane >> 4;
            int tap = s * 8 + kg * 2 + (j >> 2);
            int c = j & 3;
            c1g[idx] = (c < 3) ? f2bf(cw1[((size_t)(o * 3 + c)) * 16 + tap]) : (ushort)0;
        }
    } else if (b < 72) {
        conv_frag_elem(cw2, c2g, (b - 8) * 256 + t, 32, 32);
    } else if (b < 200) {
        conv_frag_elem(cw3, c3g, (b - 72) * 256 + t, 32, 64);
    } else if (b < 456) {
        conv_frag_elem(cw4, c4g, (b - 200) * 256 + t, 64, 64);
    } else if (b < 712) {
        deconv_frag_elem(dw1, d1g, (b - 456) * 256 + t, 64, 64);
    } else if (b < 840) {
        deconv_frag_elem(dw2, d2g, (b - 712) * 256 + t, 64, 32);
    } else if (b < 904) {
        deconv_frag_elem(dw3, d3g, (b - 840) * 256 + t, 32, 32);
    } else if (b < 936) {           // deconv_last frag: 9 nb x K32 x N16 (cls,och)
        int idx = (b - 904) * 256 + t;
        if (idx < 4608) {
            int jj = idx & 7; int lane = (idx >> 3) & 63; int nbi = idx >> 9; // 0..8
            int dy = nbi / 3, dx = nbi % 3;
            int j = lane & 15;
            int k = (lane >> 4) * 8 + jj;
            int cls = j >> 2, och = j & 3;
            int py = cls >> 1, px = cls & 1;
            int a2 = dy - py, b2 = dx - px;
            ushort v = 0;
            if (och < 3 && (unsigned)a2 < 2u && (unsigned)b2 < 2u) {
                int tap = (py + 2 * a2) * 4 + (px + 2 * b2);
                v = f2bf(dw4[((size_t)(och * 32 + k)) * 16 + tap]);
            }
            d4g[idx] = v;
        }
    } else if (b < 1686) {          // encoder winT bf16 [L,D,K*S]
        int idx = (b - 936) * 256 + t;
        if (idx < 192000) {
            int ks = idx % 100;
            int d = (idx / 100) % 192;
            int l = idx / 19200;
            int k = ks / 10, s = ks % 10;
            encwTb[idx] = f2bf(ein_w[(size_t)l * 19200 + k * 1920 + d * 10 + s]);
        }
    } else if (b < 2454) {          // fc1 frag
        int idx = (b - 1686) * 256 + t;
        int jj = idx & 7; int lane = (idx >> 3) & 63; int rest = idx >> 9;
        int nt = rest % 12, s = rest / 12;
        int k_nat = s * 32 + (lane >> 4) * 8 + jj;
        int d = (k_nat & 63) * 16 + (k_nat >> 6);
        int j = nt * 16 + (lane & 15);
        fc1g[idx] = f2bf(fc_w[(size_t)d * 192 + j]);
    } else if (b < 3222) {          // dfc frag
        int idx = (b - 2454) * 256 + t;
        int jj = idx & 7; int lane = (idx >> 3) & 63; int rest = idx >> 9;
        int nt = rest % 64, s = rest / 64;
        int k = s * 32 + (lane >> 4) * 8 + jj;
        int j_nat = nt * 16 + (lane & 15);
        int d = (j_nat & 63) * 16 + (j_nat >> 6);
        dfcg[idx] = f2bf(dfc_w[(size_t)k * 1024 + d]);
    } else {                        // b < 4246: x NCHW f32 -> NHWC-pad4 bf16
        const int n = b - 3222;
        const float* xb = x + (size_t)n * 12288;
        ushort* ob = xh + ((size_t)n << 14);
        #pragma unroll
        for (int i = 0; i < 4; ++i) {
            const int p0 = (i * 256 + t) << 2;   // 4 pixels
            const float4 v0 = *(const float4*)(xb + p0);
            const float4 v1 = *(const float4*)(xb + 4096 + p0);
            const float4 v2 = *(const float4*)(xb + 8192 + p0);
            short8 o0, o1;
            o0[0] = (short)f2bf(v0.x); o0[1] = (short)f2bf(v1.x); o0[2] = (short)f2bf(v2.x); o0[3] = 0;
            o0[4] = (short)f2bf(v0.y); o0[5] = (short)f2bf(v1.y); o0[6] = (short)f2bf(v2.y); o0[7] = 0;
            o1[0] = (short)f2bf(v0.z); o1[1] = (short)f2bf(v1.z); o1[2] = (short)f2bf(v2.z); o1[3] = 0;
            o1[4] = (short)f2bf(v0.w); o1[5] = (short)f2bf(v1.w); o1[6] = (short)f2bf(v2.w); o1[7] = 0;
            *(short8*)(ob + (size_t)(p0 << 2)) = o0;
            *(short8*)(ob + (size_t)(p0 << 2) + 8) = o1;
        }
    }
}

// ---- FUSED conv1+conv2: xh NHWC bf16 [B,64,64,4] -> bufB [B,16,16,32] -----
// B*2 blocks x 512 threads (8 waves). Phase A: conv1 rows my = 16h-1..16h+16
// into LDS mid[576][40] bf16; one 8B load per tap (4 loads/gather, 0 cvt).
// Phase B: conv2 output rows [8h, 8h+8).
__global__ __launch_bounds__(512)
void conv12_fused(const ushort* __restrict__ xh, const ushort* __restrict__ w1frag,
                  const float* __restrict__ b1, const ushort* __restrict__ w2frag,
                  const float* __restrict__ b2, ushort* __restrict__ out) {
    __shared__ ushort mid[576 * 40];   // 46080 B
    const int t = threadIdx.x;
    const int lane = t & 63, w = t >> 6;   // w in [0,8)
    const int m = lane & 15, kg = lane >> 4;
    const int h = blockIdx.x & 1, n = blockIdx.x >> 1;
    const int base = 16 * h - 1;
    const ushort* xb = xh + ((size_t)n << 14);

    short8 bf1[4];
    #pragma unroll
    for (int f = 0; f < 4; ++f)
        bf1[f] = *(const short8*)(w1frag + (f << 9) + lane * 8);

    auto gatherA = [&](int mt, short8* av) {
        const int lp = mt * 16 + m;
        const int lx = lp & 31, lyy = lp >> 5;
        const int my = base + lyy;
        const int iy0 = 2 * my - 1, ix0 = 2 * lx - 1;
        #pragma unroll
        for (int s = 0; s < 2; ++s) {
            union { ushort4v h4[2]; short8 s8; } a;
            #pragma unroll
            for (int tt = 0; tt < 2; ++tt) {
                const int tap = s * 8 + kg * 2 + tt;
                const int ky = tap >> 2, kx = tap & 3;
                const int iy = iy0 + ky, ix = ix0 + kx;
                ushort4v v = {0, 0, 0, 0};
                if ((unsigned)iy < 64u && (unsigned)ix < 64u)
                    v = *(const ushort4v*)(xb + (size_t)(((iy << 6) + ix) << 2));
                a.h4[tt] = v;
            }
            av[s] = a.s8;
        }
    };
    auto commitA = [&](int mt, short8* av) {
        f32x4 acc[2] = {{0,0,0,0},{0,0,0,0}};
        #pragma unroll
        for (int s = 0; s < 2; ++s)
            #pragma unroll
            for (int nt = 0; nt < 2; ++nt)
                acc[nt] = __builtin_amdgcn_mfma_f32_16x16x32_bf16(av[s], bf1[s * 2 + nt], acc[nt], 0, 0, 0);
        #pragma unroll
        for (int nt = 0; nt < 2; ++nt) {
            const int och = (nt << 4) + m;
            const float bv = b1[och];
            #pragma unroll
            for (int r = 0; r < 4; ++r) {
                const int lpr = (mt << 4) + (kg << 2) + r;
                mid[(size_t)lpr * 40 + och] = f2bf(fmaxf(acc[nt][r] + bv, 0.f));
            }
        }
    };

    // -------- phase A: 36 mtiles / 8 waves, 2-way unrolled -----
    {
        short8 avA[2], avB[2];
        gatherA(w, avA);
        gatherA(w + 8, avB);
        commitA(w, avA);
        commitA(w + 8, avB);
        gatherA(w + 16, avA);
        gatherA(w + 24, avB);
        commitA(w + 16, avA);
        commitA(w + 24, avB);
        if (w < 4) {
            gatherA(w + 32, avA);
            commitA(w + 32, avA);
        }
    }
    __syncthreads();
    // -------- phase B: conv2, 16 combos / 8 waves --------
    for (int it = 0; it < 2; ++it) {
        const int u = it * 8 + w;            // 0..15
        const int nt = u & 1, mt2 = u >> 1;  // mt2 0..7
        const int p2 = (mt2 << 4) + m;
        const int ox2 = p2 & 15, ly2 = p2 >> 4;
        const int oy2 = 8 * h + ly2;
        const int iy0 = 2 * oy2 - 1, ix0 = 2 * ox2 - 1;
        f32x4 acc = {0, 0, 0, 0};
        const ushort* wl = w2frag + ((size_t)nt << 9) + lane * 8;
        #pragma unroll
        for (int ky = 0; ky < 4; ++ky) {
            const int iy = iy0 + ky;
            const bool vy = (unsigned)iy < 32u;
            const int liy = iy - base;
            #pragma unroll
            for (int kx = 0; kx < 4; ++kx) {
                const int ix = ix0 + kx;
                const bool v = vy && ((unsigned)ix < 32u);
                short8 a = {0, 0, 0, 0, 0, 0, 0, 0};
                if (v) a = *(const short8*)(mid + (size_t)((liy << 5) + ix) * 40 + kg * 8);
                const short8 b = *(const short8*)(wl + ((size_t)((ky * 4 + kx) * 2) << 9));
                acc = __builtin_amdgcn_mfma_f32_16x16x32_bf16(a, b, acc, 0, 0, 0);
            }
        }
        const int och = (nt << 4) + m;
        const float bv = b2[och];
        ushort* ob = out + ((size_t)n * 256 + 128 * h + (mt2 << 4) + (kg << 2)) * 32;
        #pragma unroll
        for (int r = 0; r < 4; ++r)
            ob[r * 32 + och] = f2bf(fmaxf(acc[r] + bv, 0.f));
    }
}

// ---- FUSED conv3+conv4: bufB [B,16,16,32] -> bufD [B*16][64] --------------
__global__ __launch_bounds__(256)
void conv34_fused(const ushort* __restrict__ in, const ushort* __restrict__ w3frag,
                  const float* __restrict__ b3, const ushort* __restrict__ w4frag,
                  const float* __restrict__ b4, ushort* __restrict__ out) {
    __shared__ ushort mid[64 * 64];   // 8192 B
    const int t = threadIdx.x;
    const int lane = t & 63, w = t >> 6;
    const int m = lane & 15, kg = lane >> 4;
    const int n = blockIdx.x;
    const ushort* ibase = in + ((size_t)n << 13);   // 16*16*32

    // -------- phase A: conv3 (CIN=32,COUT=64,HIN=16) --------
    {
        const int p = (w << 4) + m;          // pixel 0..63
        const int ox = p & 7, oy = p >> 3;
        const int iy0 = 2 * oy - 1, ix0 = 2 * ox - 1;
        f32x4 acc[4] = {{0,0,0,0},{0,0,0,0},{0,0,0,0},{0,0,0,0}};
        #pragma unroll
        for (int ky = 0; ky < 4; ++ky) {
            const int iy = iy0 + ky;
            const bool vy = (unsigned)iy < 16u;
            #pragma unroll
            for (int kx = 0; kx < 4; ++kx) {
                const int ix = ix0 + kx;
                const bool v = vy && ((unsigned)ix < 16u);
                short8 a = {0, 0, 0, 0, 0, 0, 0, 0};
                if (v) a = *(const short8*)(ibase + (size_t)((iy << 4) + ix) * 32 + kg * 8);
                const int tap = ky * 4 + kx;
                #pragma unroll
                for (int nt = 0; nt < 4; ++nt) {
                    const short8 b = *(const short8*)(w3frag + ((size_t)(tap * 4 + nt) << 9) + lane * 8);
                    acc[nt] = __builtin_amdgcn_mfma_f32_16x16x32_bf16(a, b, acc[nt], 0, 0, 0);
                }
            }
        }
        #pragma unroll
        for (int nt = 0; nt < 4; ++nt) {
            const int och = (nt << 4) + m;
            const float bv = b3[och];
            #pragma unroll
            for (int r = 0; r < 4; ++r) {
                const int pr = (w << 4) + (kg << 2) + r;
                mid[(size_t)pr * 64 + och] = f2bf(fmaxf(acc[nt][r] + bv, 0.f));
            }
        }
    }
    __syncthreads();
    // -------- phase B: conv4 (CIN=64,COUT=64,HIN=8), wave = ntile --------
    {
        const int ox = m & 3, oy = m >> 2;
        const int iy0 = 2 * oy - 1, ix0 = 2 * ox - 1;
        f32x4 acc = {0, 0, 0, 0};
        const ushort* wl = w4frag + ((size_t)w << 9) + lane * 8;
        #pragma unroll
        for (int ky = 0; ky < 4; ++ky) {
            const int iy = iy0 + ky;
            const bool vy = (unsigned)iy < 8u;
            #pragma unroll
            for (int kx = 0; kx < 4; ++kx) {
                const int ix = ix0 + kx;
                const bool v = vy && ((unsigned)ix < 8u);
                const int tap = ky * 4 + kx;
                #pragma unroll
                for (int ch = 0; ch < 2; ++ch) {
                    short8 a = {0, 0, 0, 0, 0, 0, 0, 0};
                    if (v) a = *(const short8*)(mid + (size_t)((iy << 3) + ix) * 64 + ch * 32 + kg * 8);
                    const short8 b = *(const short8*)(wl + ((size_t)((tap * 2 + ch) * 4) << 9));
                    acc = __builtin_amdgcn_mfma_f32_16x16x32_bf16(a, b, acc, 0, 0, 0);
                }
            }
        }
        const int och = (w << 4) + m;
        const float bv = b4[och];
        #pragma unroll
        for (int r = 0; r < 4; ++r)
            out[((size_t)n * 16 + (kg << 2) + r) * 64 + och] = f2bf(fmaxf(acc[r] + bv, 0.f));
    }
}

// ---- FUSED deconv1+deconv2: bufD [B][4,4,64] -> bufB [B,16,16,32] ---------
__global__ __launch_bounds__(256)
void deconv12_fused(const ushort* __restrict__ in, const ushort* __restrict__ w1frag,
                    const float* __restrict__ b1, const ushort* __restrict__ w2frag,
                    const float* __restrict__ b2, ushort* __restrict__ out) {
    __shared__ ushort mid[64 * 64];   // 8192 B
    const int t = threadIdx.x;
    const int lane = t & 63, w = t >> 6;
    const int m = lane & 15, kg = lane >> 4;
    const int n = blockIdx.x;
    const ushort* ibase = in + ((size_t)n << 10);   // 4*4*64

    // -------- phase A: deconv1 (CIN=64,COUT=64,HIN=4), wave = ntile --------
    {
        const int oxh = m & 3, oyh = m >> 2;
        f32x4 acc[4] = {{0,0,0,0},{0,0,0,0},{0,0,0,0},{0,0,0,0}};
        const ushort* wl = w1frag + ((size_t)w << 9) + lane * 8;
        #pragma unroll
        for (int ch = 0; ch < 2; ++ch) {
            short8 nb[3][3];
            #pragma unroll
            for (int dy = 0; dy < 3; ++dy) {
                const int iy = oyh + dy - 1;
                const bool vy = (unsigned)iy < 4u;
                #pragma unroll
                for (int dx = 0; dx < 3; ++dx) {
                    const int ix = oxh + dx - 1;
                    short8 a = {0, 0, 0, 0, 0, 0, 0, 0};
                    if (vy && (unsigned)ix < 4u)
                        a = *(const short8*)(ibase + (size_t)((iy << 2) + ix) * 64 + ch * 32 + kg * 8);
                    nb[dy][dx] = a;
                }
            }
            #pragma unroll
            for (int cls = 0; cls < 4; ++cls) {
                const int py = cls >> 1, px = cls & 1;
                #pragma unroll
                for (int ti = 0; ti < 4; ++ti) {
                    const int a2 = ti >> 1, b2i = ti & 1;
                    const short8 b = *(const short8*)(wl + ((size_t)(((cls * 4 + ti) * 2 + ch) * 4) << 9));
                    acc[cls] = __builtin_amdgcn_mfma_f32_16x16x32_bf16(nb[py + a2][px + b2i], b, acc[cls], 0, 0, 0);
                }
            }
        }
        const int och = (w << 4) + m;
        const float bv = b1[och];
        #pragma unroll
        for (int cls = 0; cls < 4; ++cls) {
            const int py = cls >> 1, px = cls & 1;
            #pragma unroll
            for (int r = 0; r < 4; ++r) {
                const int qq = (kg << 2) + r;
                const int oxh2 = qq & 3, oyh2 = qq >> 2;
                const int oy = 2 * oyh2 + py, ox = 2 * oxh2 + px;
                mid[(size_t)((oy << 3) + ox) * 64 + och] = f2bf(fmaxf(acc[cls][r] + bv, 0.f));
            }
        }
    }
    __syncthreads();
    // -------- phase B: deconv2 (CIN=64,COUT=32,HIN=8), 8 combos / 4 waves --
    for (int u = w; u < 8; u += 4) {
        const int nt = u & 1, mt = u >> 1;
        const int q = (mt << 4) + m;
        const int oxh = q & 7, oyh = q >> 3;
        f32x4 acc[4] = {{0,0,0,0},{0,0,0,0},{0,0,0,0},{0,0,0,0}};
        const ushort* wl = w2frag + ((size_t)nt << 9) + lane * 8;
        #pragma unroll
        for (int ch = 0; ch < 2; ++ch) {
            short8 nb[3][3];
            #pragma unroll
            for (int dy = 0; dy < 3; ++dy) {
                const int iy = oyh + dy - 1;
                const bool vy = (unsigned)iy < 8u;
                #pragma unroll
                for (int dx = 0; dx < 3; ++dx) {
                    const int ix = oxh + dx - 1;
                    short8 a = {0, 0, 0, 0, 0, 0, 0, 0};
                    if (vy && (unsigned)ix < 8u)
                        a = *(const short8*)(mid + (size_t)((iy << 3) + ix) * 64 + ch * 32 + kg * 8);
                    nb[dy][dx] = a;
                }
            }
            #pragma unroll
            for (int cls = 0; cls < 4; ++cls) {
                const int py = cls >> 1, px = cls & 1;
                #pragma unroll
                for (int ti = 0; ti < 4; ++ti) {
                    const int a2 = ti >> 1, b2i = ti & 1;
                    const short8 b = *(const short8*)(wl + ((size_t)(((cls * 4 + ti) * 2 + ch) * 2) << 9));
                    acc[cls] = __builtin_amdgcn_mfma_f32_16x16x32_bf16(nb[py + a2][px + b2i], b, acc[cls], 0, 0, 0);
                }
            }
        }
        const int och = (nt << 4) + m;
        const float bv = b2[och];
        #pragma unroll
        for (int cls = 0; cls < 4; ++cls) {
            const int py = cls >> 1, px = cls & 1;
            #pragma unroll
            for (int r = 0; r < 4; ++r) {
                const int qq = (mt << 4) + (kg << 2) + r;
                const int oxh2 = qq & 7, oyh2 = qq >> 3;
                const int oy = 2 * oyh2 + py, ox = 2 * oxh2 + px;
                out[((size_t)(n * 16 + oy) * 16 + ox) * 32 + och] = f2bf(fmaxf(acc[cls][r] + bv, 0.f));
            }
        }
    }
}

// ---- FUSED deconv3+deconv4: bufB [B,16,16,32] -> recon NCHW f32 [B,3,64,64]
// B*2 blocks x 256 threads. mid uses kg-XOR channel swizzle. Phase B
// (deconv_last) uses the 9-neighbor packed-N formulation: MFMA columns
// j = cls*4+och (12/16 used), A = the 9 nb tiles shared across all cls.
__global__ __launch_bounds__(256)
void deconv34_fused(const ushort* __restrict__ in, const ushort* __restrict__ w3frag,
                    const float* __restrict__ b3, const ushort* __restrict__ w4frag,
                    const float* __restrict__ b4, float* __restrict__ out) {
    __shared__ ushort mid[20 * 32 * 32];   // 40960 B
    const int t = threadIdx.x;
    const int lane = t & 63, w = t >> 6;
    const int m = lane & 15, kg = lane >> 4;
    const int h = blockIdx.x & 1, n = blockIdx.x >> 1;
    const int base = 16 * h - 2;
    const ushort* ibase = in + ((size_t)n << 13);   // 16*16*32

    // -------- phase A: deconv3 rows ir = 8h-1 .. 8h+8 --> mid --------
    for (int u = w; u < 20; u += 4) {
        const int nt = u & 1, mt = u >> 1;
        const int ir = 8 * h - 1 + mt;
        short8 nb[3][3];
        #pragma unroll
        for (int dy = 0; dy < 3; ++dy) {
            const int iy = ir + dy - 1;
            const bool vy = (unsigned)iy < 16u;
            #pragma unroll
            for (int dx = 0; dx < 3; ++dx) {
                const int ix = m + dx - 1;
                short8 a = {0, 0, 0, 0, 0, 0, 0, 0};
                if (vy && (unsigned)ix < 16u)
                    a = *(const short8*)(ibase + (size_t)((iy << 4) + ix) * 32 + kg * 8);
                nb[dy][dx] = a;
            }
        }
        const ushort* wl = w3frag + ((size_t)nt << 9) + lane * 8;
        f32x4 acc[4] = {{0,0,0,0},{0,0,0,0},{0,0,0,0},{0,0,0,0}};
        #pragma unroll
        for (int cls = 0; cls < 4; ++cls) {
            const int py = cls >> 1, px = cls & 1;
            #pragma unroll
            for (int ti = 0; ti < 4; ++ti) {
                const int a2 = ti >> 1, b2 = ti & 1;
                const short8 b = *(const short8*)(wl + ((size_t)((cls * 4 + ti) * 2) << 9));
                acc[cls] = __builtin_amdgcn_mfma_f32_16x16x32_bf16(nb[py + a2][px + b2], b, acc[cls], 0, 0, 0);
            }
        }
        const int och = (nt << 4) + m;
        const int ochSw = och ^ (kg << 3);   // bank swizzle (writer kg)
        const float bv = b3[och];
        #pragma unroll
        for (int cls = 0; cls < 4; ++cls) {
            const int py = cls >> 1, px = cls & 1;
            const int ly = 2 * mt + py;
            #pragma unroll
            for (int r = 0; r < 4; ++r) {
                const int ox = ((kg << 3) + 2 * r) + px;
                mid[(size_t)((ly << 5) + ox) * 32 + ochSw] = f2bf(fmaxf(acc[cls][r] + bv, 0.f));
            }
        }
    }
    __syncthreads();
    // -------- phase B: deconv_last, 9-MFMA packed-N, rows [32h, 32h+32) ----
    const int clsB = m >> 2, ochB = m & 3;       // this lane's output column
    const int pyB = clsB >> 1, pxB = clsB & 1;
    for (int it = 0; it < 8; ++it) {
        const int mt2 = it * 4 + w;
        const int oyh = 16 * h + (mt2 >> 1);
        const int oxh = ((mt2 & 1) << 4) + m;
        short8 nb[3][3];
        #pragma unroll
        for (int dy = 0; dy < 3; ++dy) {
            const int iy = oyh + dy - 1;
            const bool vy = (unsigned)iy < 32u;
            const int ly = iy - base;
            #pragma unroll
            for (int dx = 0; dx < 3; ++dx) {
                const int ix = oxh + dx - 1;
                short8 a = {0, 0, 0, 0, 0, 0, 0, 0};
                if (vy && (unsigned)ix < 32u) {
                    const int rb = (kg ^ ((ix >> 3) & 3)) << 3;   // un-swizzle
                    a = *(const short8*)(mid + (size_t)((ly << 5) + ix) * 32 + rb);
                }
                nb[dy][dx] = a;
            }
        }
        f32x4 acc = {0, 0, 0, 0};
        const ushort* wl = w4frag + lane * 8;
        #pragma unroll
        for (int dy = 0; dy < 3; ++dy)
            #pragma unroll
            for (int dx = 0; dx < 3; ++dx) {
                const short8 b = *(const short8*)(wl + ((size_t)(dy * 3 + dx) << 9));
                acc = __builtin_amdgcn_mfma_f32_16x16x32_bf16(nb[dy][dx], b, acc, 0, 0, 0);
            }
        if (ochB < 3) {
            const float bv = b4[ochB];
            float* ob = out + (size_t)n * 12288 + ochB * 4096;
            const int oy = 2 * oyh + pyB;
            #pragma unroll
            for (int r = 0; r < 4; ++r) {
                const int xp = ((mt2 & 1) << 4) + (kg << 2) + r;   // half-res x
                ob[oy * 64 + 2 * xp + pxB] = acc[r] + bv;
            }
        }
    }
}

// ---------------- fc1 MFMA: bufD [B,1024] bf16 -> bufH [B,192] f32 ---------
__global__ __launch_bounds__(256)
void fc1_mfma(const ushort* __restrict__ in, const ushort* __restrict__ frag,
              const float* __restrict__ bias, float* __restrict__ out) {
    const int lane = threadIdx.x & 63;
    const int gw = (blockIdx.x << 2) + (threadIdx.x >> 6);   // [0,768)
    const int nt = gw % 12, mt = gw / 12;
    const int m = lane & 15, kg = lane >> 4;
    const ushort* arow = in + ((size_t)(mt * 16 + m) << 10) + kg * 8;
    const ushort* wl = frag + nt * 512 + lane * 8;
    f32x4 acc0 = {0, 0, 0, 0}, acc1 = {0, 0, 0, 0};
    #pragma unroll
    for (int s = 0; s < 32; s += 2) {
        const short8 a0 = *(const short8*)(arow + s * 32);
        const short8 a1 = *(const short8*)(arow + s * 32 + 32);
        const short8 b0 = *(const short8*)(wl + ((size_t)(s * 12) << 9));
        const short8 b1 = *(const short8*)(wl + ((size_t)((s + 1) * 12) << 9));
        acc0 = __builtin_amdgcn_mfma_f32_16x16x32_bf16(a0, b0, acc0, 0, 0, 0);
        acc1 = __builtin_amdgcn_mfma_f32_16x16x32_bf16(a1, b1, acc1, 0, 0, 0);
    }
    const int j = nt * 16 + m;
    const float bv = bias[j];
    #pragma unroll
    for (int r = 0; r < 4; ++r)
        out[(size_t)(mt * 16 + kg * 4 + r) * 192 + j] = (acc0[r] + acc1[r]) + bv;
}

// --------- dfc MFMA: dbf [B,192] bf16 -> bufD [B,1024] bf16 (NHWC), relu ---
__global__ __launch_bounds__(256)
void dfc_mfma(const ushort* __restrict__ in, const ushort* __restrict__ frag,
              const float* __restrict__ bias, ushort* __restrict__ out) {
    const int lane = threadIdx.x & 63;
    const int gw = (blockIdx.x << 2) + (threadIdx.x >> 6);   // [0,1024)
    const int ntg = gw & 15, mt = gw >> 4;
    const int m = lane & 15, kg = lane >> 4;
    const ushort* arow = in + (size_t)(mt * 16 + m) * 192 + kg * 8;
    const ushort* wl = frag + ((size_t)(ntg * 4) << 9) + lane * 8;
    f32x4 acc[4] = {{0,0,0,0},{0,0,0,0},{0,0,0,0},{0,0,0,0}};
    #pragma unroll
    for (int s = 0; s < 6; ++s) {
        const short8 a = *(const short8*)(arow + s * 32);
        #pragma unroll
        for (int q = 0; q < 4; ++q) {
            const short8 b = *(const short8*)(wl + ((size_t)(s * 64 + q) << 9));
            acc[q] = __builtin_amdgcn_mfma_f32_16x16x32_bf16(a, b, acc[q], 0, 0, 0);
        }
    }
    #pragma unroll
    for (int q = 0; q < 4; ++q) {
        const int j_nat = (ntg * 4 + q) * 16 + m;
        const int d = (j_nat & 63) * 16 + (j_nat >> 6);
        const float bv = bias[d];
        #pragma unroll
        for (int r = 0; r < 4; ++r) {
            const float vv = fmaxf(acc[q][r] + bv, 0.f);
            out[((size_t)(mt * 16 + kg * 4 + r) << 10) + j_nat] = f2bf(vv);
        }
    }
}

// ---- encoder switch chain: 4 rows/block, bf16 winT, ILP-4 VALU hid --------
__global__ __launch_bounds__(256)
void enc_switch4(float* __restrict__ h,
                 const ushort* __restrict__ winTb,   // [L,192,100] bf16
                 const float* __restrict__ bin_all,  // [L,100]
                 const float* __restrict__ wout_all, // [L,K,10,192]
                 const float* __restrict__ bout_all, // [L,K,192]
                 const float* __restrict__ wsw_all,  // [L,K,10]
                 const float* __restrict__ bsw_all,  // [L,K]
                 const float* __restrict__ gn_all,   // [L,B,10]
                 int* __restrict__ yidx, float* __restrict__ gateArr) {
    const int t = threadIdx.x;
    const int b0 = blockIdx.x << 2;
    __shared__ float hold[4][192], r[4][192], part[4][200], hid[4][100], lg[4][10];
    __shared__ int yi_s[4]; __shared__ float gate_s[4];
    if (t < 192) {
        #pragma unroll
        for (int row = 0; row < 4; ++row) {
            const float v = h[(size_t)(b0 + row) * 192 + t];
            hold[row][t] = v; r[row][t] = fmaxf(v, 0.f);
        }
    }
    for (int i = 0; i < 10; ++i) {
        __syncthreads();   // r ready
        if (t < 200) {
            const int ks = (t < 100) ? t : t - 100;
            const int half = (t < 100) ? 0 : 1;
            const ushort* wp = winTb + (size_t)i * 19200 + (half * 96) * 100 + ks;
            const float* r0 = &r[0][half * 96];
            const float* r1 = &r[1][half * 96];
            const float* r2 = &r[2][half * 96];
            const float* r3 = &r[3][half * 96];
            float a0 = 0.f, a1 = 0.f, a2 = 0.f, a3 = 0.f;
            #pragma unroll
            for (int dd = 0; dd < 96; ++dd) {
                const float wv = bf2f(wp[dd * 100]);
                a0 = fmaf(r0[dd], wv, a0);
                a1 = fmaf(r1[dd], wv, a1);
                a2 = fmaf(r2[dd], wv, a2);
                a3 = fmaf(r3[dd], wv, a3);
            }
            part[0][t] = a0; part[1][t] = a1; part[2][t] = a2; part[3][t] = a3;
        }
        __syncthreads();
        if (t < 100) {
            const float bv = bin_all[i * 100 + t];
            #pragma unroll
            for (int row = 0; row < 4; ++row)
                hid[row][t] = part[row][t] + part[row][t + 100] + bv;
        }
        __syncthreads();
        if (t < 40) {
            const int row = t / 10, k = t % 10;
            const float* wsw = wsw_all + i * 100 + k * 10;
            float acc = bsw_all[i * 10 + k];
            #pragma unroll
            for (int s = 0; s < 10; ++s) acc = fmaf(hid[row][k * 10 + s], wsw[s], acc);
            lg[row][k] = acc - logf(gn_all[(size_t)i * 10240 + (b0 + row) * 10 + k] + 1e-20f);
        }
        __syncthreads();
        if (t < 4) {
            int bi = 0; float best = lg[t][0];
            #pragma unroll
            for (int k = 1; k < 10; ++k) if (lg[t][k] > best) { best = lg[t][k]; bi = k; }
            float sum = 0.f;
            #pragma unroll
            for (int k = 0; k < 10; ++k) sum += expf(lg[t][k] - best);
            const float ysoft = 1.0f / sum;
            yi_s[t] = bi;
            const float g = (1.0f - ysoft) + ysoft;
            gate_s[t] = g;
            yidx[i * 1024 + b0 + t] = bi;
            gateArr[i * 1024 + b0 + t] = g;
        }
        __syncthreads();
        if (t < 192) {
            #pragma unroll
            for (int row = 0; row < 4; ++row) {
                const int yi = yi_s[row];
                const float gate = gate_s[row];
                const float* wb = wout_all + (size_t)i * 19200 + yi * 1920 + t;
                float acc = bout_all[i * 1920 + yi * 192 + t];
                #pragma unroll
                for (int s = 0; s < 10; ++s) acc = fmaf(hid[row][yi * 10 + s], wb[s * 192], acc);
                const float nv = hold[row][t] + acc * gate;
                hold[row][t] = nv; r[row][t] = fmaxf(nv, 0.f);
            }
        }
    }
    __syncthreads();
    if (t < 192) {
        #pragma unroll
        for (int row = 0; row < 4; ++row)
            h[(size_t)(b0 + row) * 192 + t] = hold[row][t];
    }
}

// ------- fused decoder switch chain; emits bf16 relu'd state for dfc -------
__global__ __launch_bounds__(256)
void dec_switch_all(const float* __restrict__ h,
                    const float* __restrict__ win_all,   // [L,K,192,10]
                    const float* __restrict__ bin_all,   // [L,K,10]
                    const float* __restrict__ wout_all,  // [L,K,10,192]
                    const float* __restrict__ bout_all,  // [L,K,192]
                    const int* __restrict__ yidx, const float* __restrict__ gateArr,
                    ushort* __restrict__ dbf) {
    const int b = blockIdx.x, t = threadIdx.x;
    __shared__ float hold[192], r[192], part[240], hid[10];
    if (t < 192) { float v = h[(size_t)b * 192 + t]; hold[t] = v; r[t] = fmaxf(v, 0.f); }
    for (int i = 0; i < 10; ++i) {
        const int yi = yidx[i * 1024 + b];
        const float gate = gateArr[i * 1024 + b];
        __syncthreads();   // r ready
        if (t < 240) {
            const int s = t % 10, g = t / 10;     // 24 groups x 8 d's
            const float* wp = win_all + (size_t)i * 19200 + yi * 1920 + s;
            const int d0 = g * 8;
            float a0 = 0.f, a1 = 0.f;
            #pragma unroll
            for (int dd = 0; dd < 8; dd += 2) {
                a0 = fmaf(r[d0 + dd + 0], wp[(d0 + dd + 0) * 10], a0);
                a1 = fmaf(r[d0 + dd + 1], wp[(d0 + dd + 1) * 10], a1);
            }
            part[t] = a0 + a1;
        }
        __syncthreads();
        if (t < 10) {
            float acc = bin_all[i * 100 + yi * 10 + t];
            #pragma unroll
            for (int g = 0; g < 24; ++g) acc += part[g * 10 + t];
            hid[t] = acc;
        }
        __syncthreads();
        if (t < 192) {
            const float* wp = wout_all + (size_t)i * 19200 + yi * 1920 + t;
            float acc = bout_all[i * 1920 + yi * 192 + t];
            #pragma unroll
            for (int s = 0; s < 10; ++s) acc = fmaf(hid[s], wp[s * 192], acc);
            float nv = hold[t] + acc * gate;
            hold[t] = nv; r[t] = fmaxf(nv, 0.f);
        }
    }
    if (t < 192) dbf[(size_t)b * 192 + t] = f2bf(r[t]);
}

// ------- z stats + reparameterize + decoder input FC -----------------------
__global__ __launch_bounds__(192)
void zfcl_kernel(const float* __restrict__ h,
                 const float* __restrict__ mw, const float* __restrict__ mb,
                 const float* __restrict__ lw, const float* __restrict__ lb,
                 const float* __restrict__ zn,
                 const float* __restrict__ fw, const float* __restrict__ fb,
                 float* __restrict__ out_z, float* __restrict__ out_mean,
                 float* __restrict__ out_lv, float* __restrict__ dbuf) {
    const int b = blockIdx.x, t = threadIdx.x;
    __shared__ float r[192], pm[160], pl[160], zsh[10];
    for (int d = t; d < 192; d += 192) r[d] = fmaxf(h[(size_t)b * 192 + d], 0.f);
    __syncthreads();
    if (t < 160) {
        const int l = t % 10, g = t / 10;
        float am = 0.f, al = 0.f;
        #pragma unroll
        for (int d = g * 12; d < g * 12 + 12; ++d) {
            am = fmaf(r[d], mw[d * 10 + l], am);
            al = fmaf(r[d], lw[d * 10 + l], al);
        }
        pm[t] = am; pl[t] = al;
    }
    __syncthreads();
    if (t < 10) {
        float zm = mb[t], zl = lb[t];
        #pragma unroll
        for (int g = 0; g < 16; ++g) { zm += pm[g * 10 + t]; zl += pl[g * 10 + t]; }
        const float z = zn[(size_t)b * 10 + t] * expf(zl * 0.5f) + zm;
        out_mean[(size_t)b * 10 + t] = zm;
        out_lv[(size_t)b * 10 + t] = zl;
        out_z[(size_t)b * 10 + t] = z;
        zsh[t] = z;
    }
    __syncthreads();
    for (int d = t; d < 192; d += 192) {
        float acc = fb[d];
        #pragma unroll
        for (int l = 0; l < 10; ++l) acc = fmaf(zsh[l], fw[l * 192 + d], acc);
        dbuf[(size_t)b * 192 + d] = acc;
    }
}

// ---------------------------------------------------------------------------
extern "C" void kernel_launch(void* const* d_in, const int* in_sizes, int n_in,
                              void* d_out, int out_size, void* d_ws, size_t ws_size,
                              hipStream_t stream) {
    const float* x      = (const float*)d_in[0];
    const float* gnoise = (const float*)d_in[1];
    const float* znoise = (const float*)d_in[2];
    const float* cw1 = (const float*)d_in[3];  const float* cb1 = (const float*)d_in[4];
    const float* cw2 = (const float*)d_in[5];  const float* cb2 = (const float*)d_in[6];
    const float* cw3 = (const float*)d_in[7];  const float* cb3 = (const float*)d_in[8];
    const float* cw4 = (const float*)d_in[9];  const float* cb4 = (const float*)d_in[10];
    const float* fc_w = (const float*)d_in[11]; const float* fc_b = (const float*)d_in[12];
    const float* ein_w = (const float*)d_in[13]; const float* ein_b = (const float*)d_in[14];
    const float* eout_w = (const float*)d_in[15]; const float* eout_b = (const float*)d_in[16];
    const float* esw_w = (const float*)d_in[17]; const float* esw_b = (const float*)d_in[18];
    const float* mean_w = (const float*)d_in[19]; const float* mean_b = (const float*)d_in[20];
    const float* lv_w = (const float*)d_in[21]; const float* lv_b = (const float*)d_in[22];
    const float* fcl_w = (const float*)d_in[23]; const float* fcl_b = (const float*)d_in[24];
    const float* din_w = (const float*)d_in[25]; const float* din_b = (const float*)d_in[26];
    const float* dout_w = (const float*)d_in[27]; const float* dout_b = (const float*)d_in[28];
    const float* dfc_w = (const float*)d_in[29]; const float* dfc_b = (const float*)d_in[30];
    const float* dw1 = (const float*)d_in[31]; const float* db1 = (const float*)d_in[32];
    const float* dw2 = (const float*)d_in[33]; const float* db2 = (const float*)d_in[34];
    const float* dw3 = (const float*)d_in[35]; const float* db3 = (const float*)d_in[36];
    const float* dw4 = (const float*)d_in[37]; const float* db4 = (const float*)d_in[38];

    float* out = (float*)d_out;
    float* recon  = out;
    float* z_out  = out + 12582912;
    float* zm_out = z_out + 10240;
    float* zl_out = zm_out + 10240;

    char* ws = (char*)d_ws;
    ushort* xh    = (ushort*)(ws);                  // [B,64,64,4] bf16 33.6 MB
    ushort* bufB  = (ushort*)(ws + 100663296);      // [B,16,16,32] 16.8 MB
    ushort* bufD  = (ushort*)(ws + 125829120);      // [B*16][64]   2.1 MB
    float*  bufH  = (float*) (ws + 127926272);      // [B,192]
    float*  bufD2 = (float*) (ws + 128712704);      // [B,192]
    int*    yidx  = (int*)   (ws + 129499136);
    float*  gate  = (float*) (ws + 129540096);
    char*   fb    = ws + 129581056;
    ushort* c1g = (ushort*)(fb);                    //   4096 B
    ushort* c2g = (ushort*)(fb + 4096);             //  32768 B
    ushort* c3g = (ushort*)(fb + 36864);            //  65536 B
    ushort* c4g = (ushort*)(fb + 102400);           // 131072 B
    ushort* d1g = (ushort*)(fb + 233472);           // 131072 B
    ushort* d2g = (ushort*)(fb + 364544);           //  65536 B
    ushort* d3g = (ushort*)(fb + 430080);           //  32768 B
    ushort* d4g = (ushort*)(fb + 462848);           //  16384 B (9216 used)
    ushort* encwTb = (ushort*)(fb + 479232);        // 384000 B [L,192,100] bf16
    ushort* fc1g  = (ushort*)(fb + 1247232);        // 393216 B [32][12][512]
    ushort* dfcg  = (ushort*)(fb + 1640448);        // 393216 B [6][64][512]
    ushort* dbf   = (ushort*)(fb + 2033664);        // 393216 B [B,192] bf16

    // ---- weight prep + x layout transform (one dispatch, overlapped) ----
    prep_all<<<4246, 256, 0, stream>>>(cw1, cw2, cw3, cw4, dw1, dw2, dw3, dw4,
                                       ein_w, fc_w, dfc_w, x,
                                       c1g, c2g, c3g, c4g, d1g, d2g, d3g, d4g,
                                       encwTb, fc1g, dfcg, xh);

    // ---- encoder ----
    conv12_fused<<<2048, 512, 0, stream>>>(xh, c1g, cb1, c2g, cb2, bufB);
    conv34_fused<<<1024, 256, 0, stream>>>(bufB, c3g, cb3, c4g, cb4, bufD);
    fc1_mfma<<<192, 256, 0, stream>>>(bufD, fc1g, fc_b, bufH);
    enc_switch4<<<256, 256, 0, stream>>>(bufH, encwTb, ein_b, eout_w, eout_b,
                                         esw_w, esw_b, gnoise, yidx, gate);
    zfcl_kernel<<<1024, 192, 0, stream>>>(bufH, mean_w, mean_b, lv_w, lv_b,
                                          znoise, fcl_w, fcl_b,
                                          z_out, zm_out, zl_out, bufD2);
    dec_switch_all<<<1024, 256, 0, stream>>>(bufD2, din_w, din_b, dout_w, dout_b,
                                             yidx, gate, dbf);
    dfc_mfma<<<256, 256, 0, stream>>>(dbf, dfcg, dfc_b, bufD);

    // ---- decoder ----
    deconv12_fused<<<1024, 256, 0, stream>>>(bufD, d1g, db1, d2g, db2, bufB);
    deconv34_fused<<<2048, 256, 0, stream>>>(bufB, d3g, db3, d4g, db4, recon);
}